// Round 7
// baseline (5548.055 us; speedup 1.0000x reference)
//
#include <hip/hip_runtime.h>

typedef short bf16x8 __attribute__((ext_vector_type(8)));   // 8 bf16 in 4 VGPRs
typedef float f32x4  __attribute__((ext_vector_type(4)));
typedef int   i32x4  __attribute__((ext_vector_type(4)));

#define DEVINL __device__ __forceinline__

// ---------------------------------------------------------------------------
// Problem: B=256, T=128, V=10000, E=256, U=1024, 4U=4096, O=1024
// fixed ws ~18.9 MB + tc*5.25 MB (tc=1 -> 24.1 MB floor)
// ---------------------------------------------------------------------------
static constexpr size_t SZ_WIM  = 4096ull * 512 * 2;   // W img  [4096][hi256|lo256]
static constexpr size_t SZ_FCW  = 1024ull * 2048 * 2;  // fc img [1024][hi1024|lo1024]
static constexpr size_t SZ_UIM  = 8388608;             // U i8 frag img, 2 planes
static constexpr size_t SZ_HB   = 1048576;             // [2 par][2 pl][256][1024] i8
static constexpr size_t SZ_CB   = 1048576;             // c state [256][1024] f32
static constexpr size_t SZ_LEN  = 4096;
static constexpr size_t SZ_DIAG = 2048;                // prog[0..15] + flags at +256B

DEVINL unsigned short bf16rn(float x){
  unsigned u = __float_as_uint(x);
  unsigned r = (u + 0x7fffu + ((u >> 16) & 1u)) >> 16;
  return (unsigned short)r;
}
DEVINL unsigned short bf16lo(float x){
  unsigned ub = __float_as_uint(x);
  return bf16rn(x - __uint_as_float(ub & 0xffff0000u));
}
DEVINL float sigm(float x){ return 1.f / (1.f + __expf(-x)); }
DEVINL float tanhfast(float x){
  float xc = fminf(15.f, fmaxf(-15.f, x));
  float e = __expf(2.f * xc);
  return (e - 1.f) / (e + 1.f);
}

// ---------------------------------------------------------------------------
__global__ void __launch_bounds__(256) probe_fill(float* __restrict__ out, int n, float v)
{
  int i = blockIdx.x * 256 + threadIdx.x;
  if (i < n) out[i] = (i == 0) ? v : 0.f;
}

// diag: if a stage marker is missing, flood out[0..1023] with 100+stage
__global__ void __launch_bounds__(64) diag_check(const int* __restrict__ prog,
                                                 float* __restrict__ out)
{
  if (threadIdx.x == 0){
    int miss = 0;
    for (int i = 7; i >= 1; i--) if (prog[i] == 0) miss = i;
    if (miss){
      for (int k = 0; k < 1024; k++) out[k] = 100.0f + (float)miss;
    }
  }
}

// ---------------------------------------------------------------------------
__global__ void __launch_bounds__(128) len_kernel(const int* __restrict__ seq,
                                                  int* __restrict__ len,
                                                  int* __restrict__ prog)
{
  int b = blockIdx.x, t = threadIdx.x;
  if (b == 0 && t == 0) prog[1] = 1;
  int pred = (seq[b * 128 + t] != 0) ? 1 : 0;
  unsigned long long m = __ballot(pred);
  __shared__ int cnt[2];
  if ((t & 63) == 0) cnt[t >> 6] = __popcll(m);
  __syncthreads();
  if (t == 0) len[b] = cnt[0] + cnt[1];
}

// ---------------------------------------------------------------------------
// transpose f32 [Ksrc][N] -> bf16 image [N][2*Ksrc] = [hi | lo]
// ---------------------------------------------------------------------------
__global__ void __launch_bounds__(256) prep_split_img(
    const float* __restrict__ S, unsigned short* __restrict__ img, int N, int Ksrc,
    int* __restrict__ prog, int stage)
{
  __shared__ float tile[64][65];
  const int nt = N >> 6;
  const int bn = blockIdx.x % nt, bk = blockIdx.x / nt;
  const int tid = threadIdx.x;
  if (blockIdx.x == 0 && tid == 0) prog[stage] = 1;
  {
    const int kk = tid >> 6, n = tid & 63;
#pragma unroll 4
    for (int i = 0; i < 16; i++){
      int k = i * 4 + kk;
      tile[k][n] = S[(size_t)((bk << 6) + k) * N + (bn << 6) + n];
    }
  }
  __syncthreads();
  {
    const int n4 = tid >> 6, k = tid & 63;
#pragma unroll 4
    for (int i = 0; i < 16; i++){
      int n = i * 4 + n4;
      float v = tile[k][n];
      size_t rowoff = (size_t)((bn << 6) + n) * (2 * Ksrc) + (bk << 6) + k;
      img[rowoff] = (unsigned short)(__float_as_uint(v) >> 16);
      img[rowoff + Ksrc] = bf16lo(v);
    }
  }
}

// ---------------------------------------------------------------------------
// U (f32 [1024][4096]) -> i8 fragment image, 2 planes (hi,lo of 16-bit *2^17)
// [nb 64][gate 4][kt 16][pl 2][lane 64][16B]; byte j = Uq(k=kt*64+quad*16+j,
// col=gate*1024+nb*16+(lane&15))
// ---------------------------------------------------------------------------
__global__ void __launch_bounds__(256) prep_uimg(const float* __restrict__ U,
                                                 signed char* __restrict__ img,
                                                 int* __restrict__ prog)
{
  const int bid = blockIdx.x;
  const int nb = bid >> 2, nt4 = bid & 3;
  const int tid = threadIdx.x;
  if (bid == 0 && tid == 0) prog[4] = 1;
  __shared__ signed char lc[16384], ldq[16384];  // [k 1024][16 cols]
  const int colbase = nt4 * 1024 + (nb << 4);
  const int kk = tid >> 4, cc = tid & 15;
#pragma unroll 4
  for (int it = 0; it < 64; it++){
    int k = it * 16 + kk;
    float v = U[(size_t)k * 4096 + colbase + cc];
    int q = (int)rintf(v * 131072.f);            // U * 2^17
    q = q > 32639 ? 32639 : (q < -32639 ? -32639 : q);
    int a = (q + 128) >> 8;
    int d = q - (a << 8);
    lc[(k << 4) + cc]  = (signed char)a;
    ldq[(k << 4) + cc] = (signed char)d;
  }
  __syncthreads();
#pragma unroll
  for (int rep = 0; rep < 4; rep++){
    int idx = rep * 256 + tid;                   // 0..1023
    int kt = idx >> 6, lane = idx & 63;
    int n = lane & 15, quad = lane >> 4;
    union { signed char b[16]; i32x4 v; } cb_, db_;
#pragma unroll
    for (int j = 0; j < 16; j++){
      int k = (kt << 6) + (quad << 4) + j;
      cb_.b[j] = lc[(k << 4) + n];
      db_.b[j] = ldq[(k << 4) + n];
    }
    size_t base = (size_t)((((nb << 2) + nt4) * 16 + kt) * 2) * 1024;
    *(i32x4*)(img + base + (size_t)lane * 16)        = cb_.v;
    *(i32x4*)(img + base + 1024 + (size_t)lane * 16) = db_.v;
  }
}

// ---------------------------------------------------------------------------
// gates GEMM: xg[256*tc][4096] = token-gathered emb x Wimg + bias (3-product).
// ---------------------------------------------------------------------------
__global__ void __launch_bounds__(256) gemm_gates(
    const float* __restrict__ emb, const unsigned short* __restrict__ Bimg,
    const float* __restrict__ bias, float* __restrict__ D,
    const int* __restrict__ seq, int c0, int tcsh, int* __restrict__ prog)
{
  __shared__ __align__(16) char lds[16384];   // A 8KB | B 8KB
  __shared__ int stok[128];
  const int tid = threadIdx.x, lane = tid & 63, wv = tid >> 6;
  const int quad = lane >> 4, nlo = lane & 15;
  const int wm = wv & 1, wn = wv >> 1;
  const int rowbase = (blockIdx.x >> 5) << 7;   // 32 col-tiles
  const int colbase = (blockIdx.x & 31) << 7;
  const int tcm1 = (1 << tcsh) - 1;
  if (blockIdx.x == 0 && tid == 0) prog[5] = 1;
  if (tid < 128){
    int r = rowbase + tid;
    stok[tid] = seq[((r >> tcsh) << 7) + c0 + (r & tcm1)];
  }
  __syncthreads();

  f32x4 acc[4][4];
#pragma unroll
  for (int i = 0; i < 4; i++)
#pragma unroll
    for (int j = 0; j < 4; j++) acc[i][j] = (f32x4){0.f, 0.f, 0.f, 0.f};

  float4 va[2][2]; int4 vb[2];
  auto loadAB = [&](int c){
    int k0 = c * 32;
    int seg = (k0 >= 512) ? 2 : (k0 >= 256 ? 1 : 0);
    int acol = k0 - seg * 256;
    int boff = (seg == 2 ? 256 : 0) + acol;
#pragma unroll
    for (int p = 0; p < 2; p++){
      int gidx = p * 256 + tid;
      int row = gidx >> 2, sg = gidx & 3;
      const float* ap = emb + (size_t)stok[row] * 256 + acol + sg * 8;
      va[p][0] = *(const float4*)ap;
      va[p][1] = *(const float4*)(ap + 4);
      vb[p] = *(const int4*)(Bimg + (size_t)(colbase + row) * 512 + boff + sg * 8);
    }
  };
  auto writeAB = [&](int c){
    int k0 = c * 32;
    int seg = (k0 >= 512) ? 2 : (k0 >= 256 ? 1 : 0);
#pragma unroll
    for (int p = 0; p < 2; p++){
      int gidx = p * 256 + tid;
      int row = gidx >> 2, sg = gidx & 3;
      float vv[8] = {va[p][0].x, va[p][0].y, va[p][0].z, va[p][0].w,
                     va[p][1].x, va[p][1].y, va[p][1].z, va[p][1].w};
      union { unsigned short s[8]; int4 q; } pk;
      if (seg == 1){
#pragma unroll
        for (int j = 0; j < 8; j++) pk.s[j] = bf16lo(vv[j]);
      } else {
#pragma unroll
        for (int j = 0; j < 8; j++) pk.s[j] = (unsigned short)(__float_as_uint(vv[j]) >> 16);
      }
      int sw = (sg ^ ((row >> 1) & 3)) << 4;
      *(int4*)(&lds[row * 64 + sw]) = pk.q;
      *(int4*)(&lds[8192 + row * 64 + sw]) = vb[p];
    }
  };

  loadAB(0);
#pragma unroll 2
  for (int c = 0; c < 24; c++){
    __syncthreads();
    writeAB(c);
    __syncthreads();
    if (c + 1 < 24) loadAB(c + 1);
    bf16x8 af[4], bfr[4];
#pragma unroll
    for (int mt = 0; mt < 4; mt++){
      int r = wm * 64 + mt * 16 + nlo;
      af[mt] = *(const bf16x8*)(&lds[r * 64 + ((quad ^ ((r >> 1) & 3)) << 4)]);
    }
#pragma unroll
    for (int nt = 0; nt < 4; nt++){
      int r = wn * 64 + nt * 16 + nlo;
      bfr[nt] = *(const bf16x8*)(&lds[8192 + r * 64 + ((quad ^ ((r >> 1) & 3)) << 4)]);
    }
#pragma unroll
    for (int mt = 0; mt < 4; mt++)
#pragma unroll
      for (int nt = 0; nt < 4; nt++)
        acc[mt][nt] = __builtin_amdgcn_mfma_f32_16x16x32_bf16(af[mt], bfr[nt], acc[mt][nt], 0, 0, 0);
  }

  float bs[4];
#pragma unroll
  for (int nt = 0; nt < 4; nt++) bs[nt] = bias[colbase + wn * 64 + nt * 16 + nlo];
#pragma unroll
  for (int mt = 0; mt < 4; mt++)
#pragma unroll
    for (int nt = 0; nt < 4; nt++){
      int col = colbase + wn * 64 + nt * 16 + nlo;
#pragma unroll
      for (int r = 0; r < 4; r++){
        int row = rowbase + wm * 64 + mt * 16 + quad * 4 + r;
        D[(size_t)row * 4096 + col] = acc[mt][nt][r] + bs[nt];
      }
    }
}

// ---------------------------------------------------------------------------
// output GEMM: out[b*128+c0+s][1024] = ohol x fcw + fcb (3-product, K'=3072)
// ---------------------------------------------------------------------------
__global__ void __launch_bounds__(256) gemm_out(
    const unsigned short* __restrict__ ohol, const unsigned short* __restrict__ Bimg,
    const float* __restrict__ bias, float* __restrict__ D,
    int c0, int tcsh, int* __restrict__ prog)
{
  __shared__ __align__(16) char lds[16384];
  const int tid = threadIdx.x, lane = tid & 63, wv = tid >> 6;
  const int quad = lane >> 4, nlo = lane & 15;
  const int wm = wv & 1, wn = wv >> 1;
  const int rowbase = (blockIdx.x >> 3) << 7;   // 8 col-tiles
  const int colbase = (blockIdx.x & 7) << 7;
  const int tcm1 = (1 << tcsh) - 1;
  if (blockIdx.x == 0 && tid == 0) prog[7] = 1;

  f32x4 acc[4][4];
#pragma unroll
  for (int i = 0; i < 4; i++)
#pragma unroll
    for (int j = 0; j < 4; j++) acc[i][j] = (f32x4){0.f, 0.f, 0.f, 0.f};

  int4 va[2], vb[2];
  auto loadAB = [&](int c){
    int k0 = c * 32;
    int seg = (k0 >= 2048) ? 2 : (k0 >= 1024 ? 1 : 0);
    int acol = k0 - seg * 1024;
    int aoff = (seg == 1 ? 1024 : 0) + acol;
    int boff = (seg == 2 ? 1024 : 0) + acol;
#pragma unroll
    for (int p = 0; p < 2; p++){
      int gidx = p * 256 + tid;
      int row = gidx >> 2, sg = gidx & 3;
      va[p] = *(const int4*)(ohol + (size_t)(rowbase + row) * 2048 + aoff + sg * 8);
      vb[p] = *(const int4*)(Bimg + (size_t)(colbase + row) * 2048 + boff + sg * 8);
    }
  };
  auto writeAB = [&](){
#pragma unroll
    for (int p = 0; p < 2; p++){
      int gidx = p * 256 + tid;
      int row = gidx >> 2, sg = gidx & 3;
      int sw = (sg ^ ((row >> 1) & 3)) << 4;
      *(int4*)(&lds[row * 64 + sw]) = va[p];
      *(int4*)(&lds[8192 + row * 64 + sw]) = vb[p];
    }
  };

  loadAB(0);
#pragma unroll 2
  for (int c = 0; c < 96; c++){
    __syncthreads();
    writeAB();
    __syncthreads();
    if (c + 1 < 96) loadAB(c + 1);
    bf16x8 af[4], bfr[4];
#pragma unroll
    for (int mt = 0; mt < 4; mt++){
      int r = wm * 64 + mt * 16 + nlo;
      af[mt] = *(const bf16x8*)(&lds[r * 64 + ((quad ^ ((r >> 1) & 3)) << 4)]);
    }
#pragma unroll
    for (int nt = 0; nt < 4; nt++){
      int r = wn * 64 + nt * 16 + nlo;
      bfr[nt] = *(const bf16x8*)(&lds[8192 + r * 64 + ((quad ^ ((r >> 1) & 3)) << 4)]);
    }
#pragma unroll
    for (int mt = 0; mt < 4; mt++)
#pragma unroll
      for (int nt = 0; nt < 4; nt++)
        acc[mt][nt] = __builtin_amdgcn_mfma_f32_16x16x32_bf16(af[mt], bfr[nt], acc[mt][nt], 0, 0, 0);
  }

  float bs[4];
#pragma unroll
  for (int nt = 0; nt < 4; nt++) bs[nt] = bias[colbase + wn * 64 + nt * 16 + nlo];
#pragma unroll
  for (int mt = 0; mt < 4; mt++)
#pragma unroll
    for (int nt = 0; nt < 4; nt++){
      int col = colbase + wn * 64 + nt * 16 + nlo;
#pragma unroll
      for (int r = 0; r < 4; r++){
        int row = rowbase + wm * 64 + mt * 16 + quad * 4 + r;
        int drow = ((row >> tcsh) << 7) + c0 + (row & tcm1);
        D[(size_t)drow * 1024 + col] = acc[mt][nt][r] + bs[nt];
      }
    }
}

// ---------------------------------------------------------------------------
// per-mb-group FLAG-ARRAY barrier (64 WGs) with WRITER-SIDE RELEASE.
// R6 post-mortem: sc1-WT h-stores' vmcnt retires at L2-accept, NOT at MALL;
// a relaxed flag STORE outran the h-data (R2's race re-introduced once the
// R5 counter's serialized-RMW delay was removed).  Empirical matrix:
//   R1/R5 relaxed RMW counter + WT h + acquire fence  -> PASS (delay masked)
//   R3    RELEASE RMW + PLAIN h (wbl2-ack)            -> PASS (proven release)
//   R2/R6 relaxed store/no-release                    -> FAIL
// Protocol here (R3's release + R6's O(1) flag array + R1's reader inv):
//   - h stores PLAIN (dirty in writer's XCD L2, best coalescing).
//   - arrive: RELEASE agent store to the WG's OWN flag word -> lowers to
//     vmcnt(0) + buffer_wbl2 sc1 (ACKED) + store: all h-writes AT the MALL
//     before the flag is visible.  No RMW, no same-line contention.
//   - wait: wave 0 polls all 64 flags IN PARALLEL (lane i -> flag[i]).
//   - ONE acquire agent fence (L1+L2 inv) per WG per step after the poll
//     (REQUIRED: parity h addresses are reused; reader L2 may hold t-2 data).
// flags[mb][0..63]: 256B per group, groups 256B apart -> no false sharing.
// ---------------------------------------------------------------------------
DEVINL void mbbar(int* flags, int nb, int t, int wv, int lane){
  __syncthreads();   // every wave's h-stores vmcnt-drained (dirty in L2)
  if (wv == 0){
    if (lane == 0)
      __hip_atomic_store(&flags[nb], t + 1, __ATOMIC_RELEASE, __HIP_MEMORY_SCOPE_AGENT);
    const int tgt = t + 1;
    for (;;){
      int v = __hip_atomic_load(&flags[lane], __ATOMIC_RELAXED, __HIP_MEMORY_SCOPE_AGENT);
      if (__ballot(v >= tgt) == ~0ull) break;
      __builtin_amdgcn_s_sleep(1);
    }
    __builtin_amdgcn_fence(__ATOMIC_ACQUIRE, "agent");  // single L1+L2 inv
  }
  __syncthreads();
}

// ---------------------------------------------------------------------------
// persistent LSTM recurrence, tc steps/launch.  256 WGs x 512 thr = 4 mb x 64 nb.
// 8 waves/WG = mh(2) x gate(4); per-lane U-frags Bf[16][2] = 128 VGPRs,
// c-loop FULLY UNROLLED (compile-time Bf indices — rule #20; R5 proven).
// R7: flag-array barrier w/ writer release (above); plain h stores;
// 2-deep h-load pipeline (load c+2 during iter c).
// h,U 2-plane i8 fixed point (h*32512 = 256a+d; U*2^17 = 256c+e); exact i32.
// ---------------------------------------------------------------------------
__global__ void __launch_bounds__(512, 2) lstm_rec(
    const float* __restrict__ xg,        // [256*tc][4096] f32, row = b*tc+s
    const signed char* __restrict__ uimg,
    const int* __restrict__ len,
    signed char* __restrict__ hb,        // [2 par][2 pl][256][1024] i8
    float* __restrict__ cbuf,            // [256][1024] f32
    unsigned short* __restrict__ ohol,   // [256*tc][hi1024|lo1024]
    int* __restrict__ barbase,           // flags[mb] at barbase + mb*64 ints
    int* __restrict__ prog,
    int c0, int tcsh)
{
  // LDS: [0,16384) h tile (2 pl x 64 r x 128B); [16384,32768) xg f32 [64][64];
  //      [32768,50176) z f32 [64][68]
  __shared__ __align__(16) char lds[50176];
  const int tc = 1 << tcsh;
  const int wg = blockIdx.x, mb = wg >> 6, nb = wg & 63;
  const int tid = threadIdx.x, lane = tid & 63, wv = tid >> 6;  // wv 0..7
  const int quad = lane >> 4, nlo = lane & 15;
  const int mh = wv & 1, g = wv >> 1;                           // gate 0..3
  int* flags = barbase + (mb << 6);
  if (wg == 0 && tid == 0) prog[6] = 1;

  // ---- U fragments -> registers: gate g, u-block nb, 16 kt x 2 planes ----
  i32x4 Bf[16][2];
#pragma unroll
  for (int kt = 0; kt < 16; kt++)
#pragma unroll
    for (int pl = 0; pl < 2; pl++){
      size_t off = (size_t)((((nb << 2) + g) * 16 + kt) * 2 + pl);
      off = (off * 64 + lane) << 4;
      Bf[kt][pl] = *(const i32x4*)(uimg + off);
    }

  const int uu = tid & 15, qq = tid >> 4;        // qq 0..31
  const int ucol = (nb << 4) + uu;
  float cst[2], hst[2];
  int lenr[2];
#pragma unroll
  for (int r = 0; r < 2; r++){
    int bglob = (mb << 6) + (qq << 1) + r;
    lenr[r] = len[bglob];
    cst[r] = cbuf[(size_t)bglob * 1024 + ucol];
    int a  = hb[((size_t)((c0 & 1) * 2 + 0) * 256 + bglob) * 1024 + ucol];
    int b_ = hb[((size_t)((c0 & 1) * 2 + 1) * 256 + bglob) * 1024 + ucol];
    hst[r] = (float)(a * 256 + b_) * (1.0f / 32512.0f);
  }

  // xg prefetch: issued before mbbar so HBM latency hides under the spin.
  float4 xreg[2];
  auto load_x = [&](int s){
#pragma unroll
    for (int it = 0; it < 2; it++){
      int idx = it * 512 + tid;
      int row = idx >> 4, c4 = idx & 15;
      xreg[it] = *(const float4*)(xg + (size_t)((((mb << 6) + row) << tcsh) + s) * 4096
                                  + (c4 >> 2) * 1024 + (nb << 4) + ((c4 & 3) << 2));
    }
  };
  load_x(0);

  const int hg = tid & 7, hr = (tid >> 3) & 63;   // tid<512 -> it selects plane

#pragma unroll 1
  for (int s = 0; s < tc; s++){
    const int t = c0 + s;
    const int par = t & 1, par2 = par ^ 1;
    const signed char* hsrc = hb + ((size_t)par * 512 + (size_t)(mb << 6)) * 1024;

    i32x4 accH[2], accM[2], accL[2];
#pragma unroll
    for (int m = 0; m < 2; m++){
      accH[m] = (i32x4){0,0,0,0};
      accM[m] = (i32x4){0,0,0,0};
      accL[m] = (i32x4){0,0,0,0};
    }

    int4 hregA[2], hregB[2];
    auto load_hto = [&](int c, int4* dst){
#pragma unroll
      for (int it = 0; it < 2; it++){
        dst[it] = *(const int4*)(hsrc + ((size_t)(it * 256 + hr)) * 1024 + c * 128 + hg * 16);
      }
    };
    auto write_hf = [&](const int4* src){
#pragma unroll
      for (int it = 0; it < 2; it++){
        *(int4*)(&lds[it * 8192 + hr * 128 + ((hg ^ (hr & 7)) << 4)]) = src[it];
      }
    };

    load_hto(0, hregA);
    load_hto(1, hregB);

#pragma unroll                         // FULL unroll: Bf[kt] compile-time
    for (int c = 0; c < 8; c++){
      __syncthreads();
      if ((c & 1) == 0) write_hf(hregA); else write_hf(hregB);
      if (c == 0){
#pragma unroll
        for (int it = 0; it < 2; it++){
          int idx = it * 512 + tid;
          int row = idx >> 4, c4 = idx & 15;
          *(float4*)(&lds[16384 + row * 256 + c4 * 16]) = xreg[it];
        }
      }
      __syncthreads();
      if (c + 2 < 8){
        if ((c & 1) == 0) load_hto(c + 2, hregA); else load_hto(c + 2, hregB);
      }
#pragma unroll
      for (int kt2 = 0; kt2 < 2; kt2++){
        const int kt = c * 2 + kt2;
        i32x4 Af[2][2];
#pragma unroll
        for (int m = 0; m < 2; m++)
#pragma unroll
          for (int pl = 0; pl < 2; pl++){
            int hrow = (mh << 5) + (m << 4) + nlo;
            int sgl = ((kt2 << 2) + quad) ^ (hrow & 7);
            Af[m][pl] = *(const i32x4*)(&lds[pl * 8192 + hrow * 128 + (sgl << 4)]);
          }
#pragma unroll
        for (int m = 0; m < 2; m++){
          accH[m] = __builtin_amdgcn_mfma_i32_16x16x64_i8(Af[m][0], Bf[kt][0], accH[m], 0, 0, 0);
          accM[m] = __builtin_amdgcn_mfma_i32_16x16x64_i8(Af[m][0], Bf[kt][1], accM[m], 0, 0, 0);
          accM[m] = __builtin_amdgcn_mfma_i32_16x16x64_i8(Af[m][1], Bf[kt][0], accM[m], 0, 0, 0);
          accL[m] = __builtin_amdgcn_mfma_i32_16x16x64_i8(Af[m][1], Bf[kt][1], accL[m], 0, 0, 0);
        }
      }
    }
    __syncthreads();

    // prefetch next step's xg under the z/elementwise/barrier phases
    if (s + 1 < tc) load_x(s + 1);

    // ---- z = (65536*accH + 256*accM + accL)/(32512*2^17) -> LDS ----
    const float cH = 1.0f / 65024.0f;
    const float cM = 1.0f / 16646144.0f;
    const float cL = 1.0f / 4261412864.0f;
#pragma unroll
    for (int m = 0; m < 2; m++){
#pragma unroll
      for (int r = 0; r < 4; r++){
        float z = (float)accH[m][r] * cH
                + (float)accM[m][r] * cM
                + (float)accL[m][r] * cL;
        int zrow = (mh << 5) + (m << 4) + (quad << 2) + r;
        *(float*)(&lds[32768 + (((zrow * 68) + g * 16 + nlo) << 2)]) = z;
      }
    }
    __syncthreads();

#pragma unroll
    for (int r = 0; r < 2; r++){
      int zrow = (qq << 1) + r;
      int bglob = (mb << 6) + zrow;
      float zi = *(const float*)(&lds[32768 + (((zrow * 68) + 0  + uu) << 2)])
               + *(const float*)(&lds[16384 + (((zrow << 6) + 0  + uu) << 2)]);
      float zf = *(const float*)(&lds[32768 + (((zrow * 68) + 16 + uu) << 2)])
               + *(const float*)(&lds[16384 + (((zrow << 6) + 16 + uu) << 2)]);
      float zg = *(const float*)(&lds[32768 + (((zrow * 68) + 32 + uu) << 2)])
               + *(const float*)(&lds[16384 + (((zrow << 6) + 32 + uu) << 2)]);
      float zo = *(const float*)(&lds[32768 + (((zrow * 68) + 48 + uu) << 2)])
               + *(const float*)(&lds[16384 + (((zrow << 6) + 48 + uu) << 2)]);
      float iv = sigm(zi), fv = sigm(zf), ov = sigm(zo), gv = tanhfast(zg);
      float cn = fv * cst[r] + iv * gv;
      float hn = ov * tanhfast(cn);
      bool vld = (t < lenr[r]);
      cst[r] = vld ? cn : cst[r];
      hst[r] = vld ? hn : hst[r];
      float ho = vld ? hn : 0.f;
      size_t orow = ((size_t)bglob << tcsh) + s;
      ohol[orow * 2048 + ucol]        = (unsigned short)(__float_as_uint(ho) >> 16);
      ohol[orow * 2048 + 1024 + ucol] = bf16lo(ho);
      int H = (int)rintf(hst[r] * 32512.f);
      H = H > 32512 ? 32512 : (H < -32512 ? -32512 : H);
      int a = (H + 128) >> 8;
      int b_ = H - (a << 8);
      // PLAIN stores (dirty in this XCD's L2); made remote-visible by mbbar's
      // RELEASE flag store (vmcnt drain + buffer_wbl2 ack) before the flag.
      hb[((size_t)(par2 * 2 + 0) * 256 + bglob) * 1024 + ucol] = (signed char)a;
      hb[((size_t)(par2 * 2 + 1) * 256 + bglob) * 1024 + ucol] = (signed char)b_;
    }
    mbbar(flags, nb, t, wv, lane);
  }

#pragma unroll
  for (int r = 0; r < 2; r++){
    int bglob = (mb << 6) + (qq << 1) + r;
    cbuf[(size_t)bglob * 1024 + ucol] = cst[r];
  }
}

// ---------------------------------------------------------------------------
extern "C" void kernel_launch(void* const* d_in, const int* in_sizes, int n_in,
                              void* d_out, int out_size, void* d_ws, size_t ws_size,
                              hipStream_t stream)
{
  const int*   seq = (const int*)  d_in[0];
  const float* emb = (const float*)d_in[1];
  const float* Wm  = (const float*)d_in[2];
  const float* Um  = (const float*)d_in[3];
  const float* bv  = (const float*)d_in[4];
  const float* fcW = (const float*)d_in[5];
  const float* fcb = (const float*)d_in[6];
  float* out = (float*)d_out;
  char* ws = (char*)d_ws;

  // marker: survives iff no kernel/memset below ever touches d_out
  hipMemsetAsync(d_out, 0x42, 256, stream);   // 64 floats = 48.566

  size_t off = 0;
  unsigned short* wim = (unsigned short*)(ws + off); off += SZ_WIM;
  unsigned short* fcw = (unsigned short*)(ws + off); off += SZ_FCW;
  signed char*    uim = (signed char*)(ws + off);    off += SZ_UIM;
  signed char*    hb  = (signed char*)(ws + off);    off += SZ_HB;
  float*          cb  = (float*)(ws + off);          off += SZ_CB;
  int*            len = (int*)(ws + off);            off += SZ_LEN;
  int*            diag= (int*)(ws + off);            off += SZ_DIAG;
  const size_t fixed = off;

  int tcsh = -1;
  for (int s = 5; s >= 0; s--)
    if (ws && fixed + (5242880ull << s) <= ws_size){ tcsh = s; break; }

  if (tcsh < 0){
    probe_fill<<<(out_size + 255) / 256, 256, 0, stream>>>(
        out, out_size, 1000.0f + (float)(ws_size >> 20));
    return;
  }
  const int tc = 1 << tcsh;

  float*          xgc  = (float*)(ws + fixed);
  unsigned short* ohol = (unsigned short*)(ws + fixed + (size_t)tc * 4194304);

  hipMemsetAsync(diag, 0, SZ_DIAG, stream);   // prog + per-mb barrier flags
  hipMemsetAsync(hb, 0, 524288, stream);      // parity-0 h planes = 0
  hipMemsetAsync(cb, 0, SZ_CB, stream);       // c state = 0

  int* prog = diag;
  int* barbase = diag + 64;                   // flags: 4 mb x 64 ints, 256B apart

  len_kernel<<<256, 128, 0, stream>>>(seq, len, prog);
  prep_split_img<<<256, 256, 0, stream>>>(Wm, wim, 4096, 256, prog, 2);
  prep_split_img<<<256, 256, 0, stream>>>(fcW, fcw, 1024, 1024, prog, 3);
  prep_uimg<<<256, 256, 0, stream>>>(Um, uim, prog);

  for (int c0 = 0; c0 < 128; c0 += tc){
    gemm_gates<<<dim3((2 * tc) * 32), 256, 0, stream>>>(emb, wim, bv, xgc, seq, c0, tcsh, prog);
    lstm_rec<<<dim3(256), 512, 0, stream>>>(xgc, uim, len, hb, cb, ohol, barbase, prog, c0, tcsh);
    gemm_out<<<dim3((2 * tc) * 8), 256, 0, stream>>>(ohol, fcw, fcb, out, c0, tcsh, prog);
  }

  diag_check<<<1, 64, 0, stream>>>(prog, out);
}

// Round 8
// 4343.496 us; speedup vs baseline: 1.2773x; 1.2773x over previous
//
#include <hip/hip_runtime.h>

typedef short bf16x8 __attribute__((ext_vector_type(8)));   // 8 bf16 in 4 VGPRs
typedef float f32x4  __attribute__((ext_vector_type(4)));
typedef int   i32x4  __attribute__((ext_vector_type(4)));

#define DEVINL __device__ __forceinline__

// ---------------------------------------------------------------------------
// Problem: B=256, T=128, V=10000, E=256, U=1024, 4U=4096, O=1024
// fixed ws ~18.9 MB + tc*5.25 MB (tc=1 -> 24.1 MB floor)
// ---------------------------------------------------------------------------
static constexpr size_t SZ_WIM  = 4096ull * 512 * 2;   // W img  [4096][hi256|lo256]
static constexpr size_t SZ_FCW  = 1024ull * 2048 * 2;  // fc img [1024][hi1024|lo1024]
static constexpr size_t SZ_UIM  = 8388608;             // U i8 frag img, 2 planes
static constexpr size_t SZ_HB   = 1048576;             // [2 par][256][1024] u16 packed (a<<8|b)
static constexpr size_t SZ_CB   = 1048576;             // c state [256][1024] f32
static constexpr size_t SZ_LEN  = 4096;
static constexpr size_t SZ_DIAG = 2048;                // prog[0..15] + flags at +256B

DEVINL unsigned short bf16rn(float x){
  unsigned u = __float_as_uint(x);
  unsigned r = (u + 0x7fffu + ((u >> 16) & 1u)) >> 16;
  return (unsigned short)r;
}
DEVINL unsigned short bf16lo(float x){
  unsigned ub = __float_as_uint(x);
  return bf16rn(x - __uint_as_float(ub & 0xffff0000u));
}
DEVINL float sigm(float x){ return 1.f / (1.f + __expf(-x)); }
DEVINL float tanhfast(float x){
  float xc = fminf(15.f, fmaxf(-15.f, x));
  float e = __expf(2.f * xc);
  return (e - 1.f) / (e + 1.f);
}

// ---------------------------------------------------------------------------
__global__ void __launch_bounds__(256) probe_fill(float* __restrict__ out, int n, float v)
{
  int i = blockIdx.x * 256 + threadIdx.x;
  if (i < n) out[i] = (i == 0) ? v : 0.f;
}

// diag: if a stage marker is missing, flood out[0..1023] with 100+stage
__global__ void __launch_bounds__(64) diag_check(const int* __restrict__ prog,
                                                 float* __restrict__ out)
{
  if (threadIdx.x == 0){
    int miss = 0;
    for (int i = 7; i >= 1; i--) if (prog[i] == 0) miss = i;
    if (miss){
      for (int k = 0; k < 1024; k++) out[k] = 100.0f + (float)miss;
    }
  }
}

// ---------------------------------------------------------------------------
__global__ void __launch_bounds__(128) len_kernel(const int* __restrict__ seq,
                                                  int* __restrict__ len,
                                                  int* __restrict__ prog)
{
  int b = blockIdx.x, t = threadIdx.x;
  if (b == 0 && t == 0) prog[1] = 1;
  int pred = (seq[b * 128 + t] != 0) ? 1 : 0;
  unsigned long long m = __ballot(pred);
  __shared__ int cnt[2];
  if ((t & 63) == 0) cnt[t >> 6] = __popcll(m);
  __syncthreads();
  if (t == 0) len[b] = cnt[0] + cnt[1];
}

// ---------------------------------------------------------------------------
// transpose f32 [Ksrc][N] -> bf16 image [N][2*Ksrc] = [hi | lo]
// ---------------------------------------------------------------------------
__global__ void __launch_bounds__(256) prep_split_img(
    const float* __restrict__ S, unsigned short* __restrict__ img, int N, int Ksrc,
    int* __restrict__ prog, int stage)
{
  __shared__ float tile[64][65];
  const int nt = N >> 6;
  const int bn = blockIdx.x % nt, bk = blockIdx.x / nt;
  const int tid = threadIdx.x;
  if (blockIdx.x == 0 && tid == 0) prog[stage] = 1;
  {
    const int kk = tid >> 6, n = tid & 63;
#pragma unroll 4
    for (int i = 0; i < 16; i++){
      int k = i * 4 + kk;
      tile[k][n] = S[(size_t)((bk << 6) + k) * N + (bn << 6) + n];
    }
  }
  __syncthreads();
  {
    const int n4 = tid >> 6, k = tid & 63;
#pragma unroll 4
    for (int i = 0; i < 16; i++){
      int n = i * 4 + n4;
      float v = tile[k][n];
      size_t rowoff = (size_t)((bn << 6) + n) * (2 * Ksrc) + (bk << 6) + k;
      img[rowoff] = (unsigned short)(__float_as_uint(v) >> 16);
      img[rowoff + Ksrc] = bf16lo(v);
    }
  }
}

// ---------------------------------------------------------------------------
// U (f32 [1024][4096]) -> i8 fragment image, 2 planes (hi,lo of 16-bit *2^17)
// [nb 64][gate 4][kt 16][pl 2][lane 64][16B]; byte j = Uq(k=kt*64+quad*16+j,
// col=gate*1024+nb*16+(lane&15))
// ---------------------------------------------------------------------------
__global__ void __launch_bounds__(256) prep_uimg(const float* __restrict__ U,
                                                 signed char* __restrict__ img,
                                                 int* __restrict__ prog)
{
  const int bid = blockIdx.x;
  const int nb = bid >> 2, nt4 = bid & 3;
  const int tid = threadIdx.x;
  if (bid == 0 && tid == 0) prog[4] = 1;
  __shared__ signed char lc[16384], ldq[16384];  // [k 1024][16 cols]
  const int colbase = nt4 * 1024 + (nb << 4);
  const int kk = tid >> 4, cc = tid & 15;
#pragma unroll 4
  for (int it = 0; it < 64; it++){
    int k = it * 16 + kk;
    float v = U[(size_t)k * 4096 + colbase + cc];
    int q = (int)rintf(v * 131072.f);            // U * 2^17
    q = q > 32639 ? 32639 : (q < -32639 ? -32639 : q);
    int a = (q + 128) >> 8;
    int d = q - (a << 8);
    lc[(k << 4) + cc]  = (signed char)a;
    ldq[(k << 4) + cc] = (signed char)d;
  }
  __syncthreads();
#pragma unroll
  for (int rep = 0; rep < 4; rep++){
    int idx = rep * 256 + tid;                   // 0..1023
    int kt = idx >> 6, lane = idx & 63;
    int n = lane & 15, quad = lane >> 4;
    union { signed char b[16]; i32x4 v; } cb_, db_;
#pragma unroll
    for (int j = 0; j < 16; j++){
      int k = (kt << 6) + (quad << 4) + j;
      cb_.b[j] = lc[(k << 4) + n];
      db_.b[j] = ldq[(k << 4) + n];
    }
    size_t base = (size_t)((((nb << 2) + nt4) * 16 + kt) * 2) * 1024;
    *(i32x4*)(img + base + (size_t)lane * 16)        = cb_.v;
    *(i32x4*)(img + base + 1024 + (size_t)lane * 16) = db_.v;
  }
}

// ---------------------------------------------------------------------------
// gates GEMM: xg[256*tc][4096] = token-gathered emb x Wimg + bias (3-product).
// ---------------------------------------------------------------------------
__global__ void __launch_bounds__(256) gemm_gates(
    const float* __restrict__ emb, const unsigned short* __restrict__ Bimg,
    const float* __restrict__ bias, float* __restrict__ D,
    const int* __restrict__ seq, int c0, int tcsh, int* __restrict__ prog)
{
  __shared__ __align__(16) char lds[16384];   // A 8KB | B 8KB
  __shared__ int stok[128];
  const int tid = threadIdx.x, lane = tid & 63, wv = tid >> 6;
  const int quad = lane >> 4, nlo = lane & 15;
  const int wm = wv & 1, wn = wv >> 1;
  const int rowbase = (blockIdx.x >> 5) << 7;   // 32 col-tiles
  const int colbase = (blockIdx.x & 31) << 7;
  const int tcm1 = (1 << tcsh) - 1;
  if (blockIdx.x == 0 && tid == 0) prog[5] = 1;
  if (tid < 128){
    int r = rowbase + tid;
    stok[tid] = seq[((r >> tcsh) << 7) + c0 + (r & tcm1)];
  }
  __syncthreads();

  f32x4 acc[4][4];
#pragma unroll
  for (int i = 0; i < 4; i++)
#pragma unroll
    for (int j = 0; j < 4; j++) acc[i][j] = (f32x4){0.f, 0.f, 0.f, 0.f};

  float4 va[2][2]; int4 vb[2];
  auto loadAB = [&](int c){
    int k0 = c * 32;
    int seg = (k0 >= 512) ? 2 : (k0 >= 256 ? 1 : 0);
    int acol = k0 - seg * 256;
    int boff = (seg == 2 ? 256 : 0) + acol;
#pragma unroll
    for (int p = 0; p < 2; p++){
      int gidx = p * 256 + tid;
      int row = gidx >> 2, sg = gidx & 3;
      const float* ap = emb + (size_t)stok[row] * 256 + acol + sg * 8;
      va[p][0] = *(const float4*)ap;
      va[p][1] = *(const float4*)(ap + 4);
      vb[p] = *(const int4*)(Bimg + (size_t)(colbase + row) * 512 + boff + sg * 8);
    }
  };
  auto writeAB = [&](int c){
    int k0 = c * 32;
    int seg = (k0 >= 512) ? 2 : (k0 >= 256 ? 1 : 0);
#pragma unroll
    for (int p = 0; p < 2; p++){
      int gidx = p * 256 + tid;
      int row = gidx >> 2, sg = gidx & 3;
      float vv[8] = {va[p][0].x, va[p][0].y, va[p][0].z, va[p][0].w,
                     va[p][1].x, va[p][1].y, va[p][1].z, va[p][1].w};
      union { unsigned short s[8]; int4 q; } pk;
      if (seg == 1){
#pragma unroll
        for (int j = 0; j < 8; j++) pk.s[j] = bf16lo(vv[j]);
      } else {
#pragma unroll
        for (int j = 0; j < 8; j++) pk.s[j] = (unsigned short)(__float_as_uint(vv[j]) >> 16);
      }
      int sw = (sg ^ ((row >> 1) & 3)) << 4;
      *(int4*)(&lds[row * 64 + sw]) = pk.q;
      *(int4*)(&lds[8192 + row * 64 + sw]) = vb[p];
    }
  };

  loadAB(0);
#pragma unroll 2
  for (int c = 0; c < 24; c++){
    __syncthreads();
    writeAB(c);
    __syncthreads();
    if (c + 1 < 24) loadAB(c + 1);
    bf16x8 af[4], bfr[4];
#pragma unroll
    for (int mt = 0; mt < 4; mt++){
      int r = wm * 64 + mt * 16 + nlo;
      af[mt] = *(const bf16x8*)(&lds[r * 64 + ((quad ^ ((r >> 1) & 3)) << 4)]);
    }
#pragma unroll
    for (int nt = 0; nt < 4; nt++){
      int r = wn * 64 + nt * 16 + nlo;
      bfr[nt] = *(const bf16x8*)(&lds[8192 + r * 64 + ((quad ^ ((r >> 1) & 3)) << 4)]);
    }
#pragma unroll
    for (int mt = 0; mt < 4; mt++)
#pragma unroll
      for (int nt = 0; nt < 4; nt++)
        acc[mt][nt] = __builtin_amdgcn_mfma_f32_16x16x32_bf16(af[mt], bfr[nt], acc[mt][nt], 0, 0, 0);
  }

  float bs[4];
#pragma unroll
  for (int nt = 0; nt < 4; nt++) bs[nt] = bias[colbase + wn * 64 + nt * 16 + nlo];
#pragma unroll
  for (int mt = 0; mt < 4; mt++)
#pragma unroll
    for (int nt = 0; nt < 4; nt++){
      int col = colbase + wn * 64 + nt * 16 + nlo;
#pragma unroll
      for (int r = 0; r < 4; r++){
        int row = rowbase + wm * 64 + mt * 16 + quad * 4 + r;
        D[(size_t)row * 4096 + col] = acc[mt][nt][r] + bs[nt];
      }
    }
}

// ---------------------------------------------------------------------------
// output GEMM: out[b*128+c0+s][1024] = ohol x fcw + fcb (3-product, K'=3072)
// ---------------------------------------------------------------------------
__global__ void __launch_bounds__(256) gemm_out(
    const unsigned short* __restrict__ ohol, const unsigned short* __restrict__ Bimg,
    const float* __restrict__ bias, float* __restrict__ D,
    int c0, int tcsh, int* __restrict__ prog)
{
  __shared__ __align__(16) char lds[16384];
  const int tid = threadIdx.x, lane = tid & 63, wv = tid >> 6;
  const int quad = lane >> 4, nlo = lane & 15;
  const int wm = wv & 1, wn = wv >> 1;
  const int rowbase = (blockIdx.x >> 3) << 7;   // 8 col-tiles
  const int colbase = (blockIdx.x & 7) << 7;
  const int tcm1 = (1 << tcsh) - 1;
  if (blockIdx.x == 0 && tid == 0) prog[7] = 1;

  f32x4 acc[4][4];
#pragma unroll
  for (int i = 0; i < 4; i++)
#pragma unroll
    for (int j = 0; j < 4; j++) acc[i][j] = (f32x4){0.f, 0.f, 0.f, 0.f};

  int4 va[2], vb[2];
  auto loadAB = [&](int c){
    int k0 = c * 32;
    int seg = (k0 >= 2048) ? 2 : (k0 >= 1024 ? 1 : 0);
    int acol = k0 - seg * 1024;
    int aoff = (seg == 1 ? 1024 : 0) + acol;
    int boff = (seg == 2 ? 1024 : 0) + acol;
#pragma unroll
    for (int p = 0; p < 2; p++){
      int gidx = p * 256 + tid;
      int row = gidx >> 2, sg = gidx & 3;
      va[p] = *(const int4*)(ohol + (size_t)(rowbase + row) * 2048 + aoff + sg * 8);
      vb[p] = *(const int4*)(Bimg + (size_t)(colbase + row) * 2048 + boff + sg * 8);
    }
  };
  auto writeAB = [&](){
#pragma unroll
    for (int p = 0; p < 2; p++){
      int gidx = p * 256 + tid;
      int row = gidx >> 2, sg = gidx & 3;
      int sw = (sg ^ ((row >> 1) & 3)) << 4;
      *(int4*)(&lds[row * 64 + sw]) = va[p];
      *(int4*)(&lds[8192 + row * 64 + sw]) = vb[p];
    }
  };

  loadAB(0);
#pragma unroll 2
  for (int c = 0; c < 96; c++){
    __syncthreads();
    writeAB();
    __syncthreads();
    if (c + 1 < 96) loadAB(c + 1);
    bf16x8 af[4], bfr[4];
#pragma unroll
    for (int mt = 0; mt < 4; mt++){
      int r = wm * 64 + mt * 16 + nlo;
      af[mt] = *(const bf16x8*)(&lds[r * 64 + ((quad ^ ((r >> 1) & 3)) << 4)]);
    }
#pragma unroll
    for (int nt = 0; nt < 4; nt++){
      int r = wn * 64 + nt * 16 + nlo;
      bfr[nt] = *(const bf16x8*)(&lds[8192 + r * 64 + ((quad ^ ((r >> 1) & 3)) << 4)]);
    }
#pragma unroll
    for (int mt = 0; mt < 4; mt++)
#pragma unroll
      for (int nt = 0; nt < 4; nt++)
        acc[mt][nt] = __builtin_amdgcn_mfma_f32_16x16x32_bf16(af[mt], bfr[nt], acc[mt][nt], 0, 0, 0);
  }

  float bs[4];
#pragma unroll
  for (int nt = 0; nt < 4; nt++) bs[nt] = bias[colbase + wn * 64 + nt * 16 + nlo];
#pragma unroll
  for (int mt = 0; mt < 4; mt++)
#pragma unroll
    for (int nt = 0; nt < 4; nt++){
      int col = colbase + wn * 64 + nt * 16 + nlo;
#pragma unroll
      for (int r = 0; r < 4; r++){
        int row = rowbase + wm * 64 + mt * 16 + quad * 4 + r;
        int drow = ((row >> tcsh) << 7) + c0 + (row & tcm1);
        D[(size_t)drow * 1024 + col] = acc[mt][nt][r] + bs[nt];
      }
    }
}

// ---------------------------------------------------------------------------
// per-mb-group FLAG-ARRAY barrier (64 WGs), PROVABLY ordered:
// h is written via RETURNING agent-scope 32-bit atomic_exchange (result
// consumed) -> vmcnt retires only when the MALL responds -> after
// __syncthreads() (vmcnt 0) ALL h-words are AT the coherence point.  The
// arrival can therefore be a plain relaxed store (O(1), no RMW serialization
// [R5's ~6-13us/step], no buffer_wbl2 [R7's 26MB/step write amplification]).
//   - wait: wave 0 polls all 64 flags IN PARALLEL (lane i -> flag[i]).
//   - ONE acquire agent fence (L1+L2 inv) per WG per step after the poll
//     (parity h addresses are reused; reader caches may hold t-2 data).
// flags[mb][0..63]: 256B per group, groups 256B apart -> no false sharing.
// ---------------------------------------------------------------------------
DEVINL void mbbar(int* flags, int nb, int t, int wv, int lane){
  __syncthreads();   // vmcnt(0) per wave: all h-exchanges RESPONDED (at MALL)
  if (wv == 0){
    if (lane == 0)
      __hip_atomic_store(&flags[nb], t + 1, __ATOMIC_RELAXED, __HIP_MEMORY_SCOPE_AGENT);
    const int tgt = t + 1;
    for (;;){
      int v = __hip_atomic_load(&flags[lane], __ATOMIC_RELAXED, __HIP_MEMORY_SCOPE_AGENT);
      if (__ballot(v >= tgt) == ~0ull) break;
      __builtin_amdgcn_s_sleep(1);
    }
    __builtin_amdgcn_fence(__ATOMIC_ACQUIRE, "agent");  // single L1+L2 inv
  }
  __syncthreads();
}

// ---------------------------------------------------------------------------
// persistent LSTM recurrence, tc steps/launch.  256 WGs x 512 thr = 4 mb x 64 nb.
// 8 waves/WG = mh(2) x gate(4); per-lane U-frags Bf[16][2] = 128 VGPRs,
// c-loop FULLY UNROLLED (compile-time Bf indices; R5 proven).
// R8: h stored as packed u16 (a<<8 | b&255) in [par][256][1024]; each thread
// writes its 2 adjacent cols as ONE returning 32-bit atomic_exchange (the
// provable-release mechanism, see mbbar).  Reader splits hi/lo planes
// in-register with v_perm after ds_read (VALU ~5% busy -> free).
// 2-deep h-load pipeline (load c+2 during iter c).
// ---------------------------------------------------------------------------
__global__ void __launch_bounds__(512, 2) lstm_rec(
    const float* __restrict__ xg,        // [256*tc][4096] f32, row = b*tc+s
    const signed char* __restrict__ uimg,
    const int* __restrict__ len,
    signed char* __restrict__ hbb,       // [2 par][256][1024] u16 packed
    float* __restrict__ cbuf,            // [256][1024] f32
    unsigned short* __restrict__ ohol,   // [256*tc][hi1024|lo1024]
    int* __restrict__ barbase,           // flags[mb] at barbase + mb*64 ints
    int* __restrict__ prog,
    int c0, int tcsh)
{
  // LDS: [0,16384) h tile [64 r][256 B] (u16 cols, 32B-block XOR swizzle);
  //      [16384,32768) xg f32 [64][64]; [32768,50176) z f32 [64][68]
  __shared__ __align__(16) char lds[50176];
  const int tc = 1 << tcsh;
  const int wg = blockIdx.x, mb = wg >> 6, nb = wg & 63;
  const int tid = threadIdx.x, lane = tid & 63, wv = tid >> 6;  // wv 0..7
  const int quad = lane >> 4, nlo = lane & 15;
  const int mh = wv & 1, g = wv >> 1;                           // gate 0..3
  int* flags = barbase + (mb << 6);
  if (wg == 0 && tid == 0) prog[6] = 1;

  const unsigned short* hb2 = (const unsigned short*)hbb;

  // ---- U fragments -> registers: gate g, u-block nb, 16 kt x 2 planes ----
  i32x4 Bf[16][2];
#pragma unroll
  for (int kt = 0; kt < 16; kt++)
#pragma unroll
    for (int pl = 0; pl < 2; pl++){
      size_t off = (size_t)((((nb << 2) + g) * 16 + kt) * 2 + pl);
      off = (off * 64 + lane) << 4;
      Bf[kt][pl] = *(const i32x4*)(uimg + off);
    }

  // ---- elementwise mapping: thread = (1 row x 2 adjacent cols) ----
  const int erow = tid >> 3;            // 0..63 local row
  const int ecp  = tid & 7;             // col-pair index
  const int ecol0 = ecp << 1;           // local col 0..14 (even)
  const int ucol0 = (nb << 4) + ecol0;  // global u col (even)
  const int bglob = (mb << 6) + erow;
  const int lenr = len[bglob];
  float cst[2], hst[2];
#pragma unroll
  for (int r = 0; r < 2; r++){
    cst[r] = cbuf[(size_t)bglob * 1024 + ucol0 + r];
    unsigned short e = hb2[((size_t)(c0 & 1) * 256 + bglob) * 1024 + ucol0 + r];
    int a = (signed char)(e >> 8), b_ = (signed char)(e & 255);
    hst[r] = (float)(a * 256 + b_) * (1.0f / 32512.0f);
  }

  // xg prefetch: issued before mbbar so HBM latency hides under the spin.
  float4 xreg[2];
  auto load_x = [&](int s){
#pragma unroll
    for (int it = 0; it < 2; it++){
      int idx = it * 512 + tid;
      int row = idx >> 4, c4 = idx & 15;
      xreg[it] = *(const float4*)(xg + (size_t)((((mb << 6) + row) << tcsh) + s) * 4096
                                  + (c4 >> 2) * 1024 + (nb << 4) + ((c4 & 3) << 2));
    }
  };
  load_x(0);

  // h staging mapping: thread = (1 row x one 32B block of 8)
  const int hrw = tid >> 3, hsub = tid & 7;

#pragma unroll 1
  for (int s = 0; s < tc; s++){
    const int t = c0 + s;
    const int par = t & 1, par2 = par ^ 1;
    // byte base of this mb's h rows for parity par
    const signed char* hsrc = hbb + ((size_t)par * 256 + (size_t)(mb << 6)) * 2048;

    i32x4 accH[2], accM[2], accL[2];
#pragma unroll
    for (int m = 0; m < 2; m++){
      accH[m] = (i32x4){0,0,0,0};
      accM[m] = (i32x4){0,0,0,0};
      accL[m] = (i32x4){0,0,0,0};
    }

    int4 hregA[2], hregB[2];
    auto load_hto = [&](int c, int4* dst){
      const signed char* p = hsrc + (size_t)hrw * 2048 + c * 256 + hsub * 32;
      dst[0] = *(const int4*)p;
      dst[1] = *(const int4*)(p + 16);
    };
    auto write_hf = [&](const int4* src){
      char* p = &lds[hrw * 256 + ((hsub ^ (hrw & 7)) << 5)];
      *(int4*)p = src[0];
      *(int4*)(p + 16) = src[1];
    };

    load_hto(0, hregA);
    load_hto(1, hregB);

#pragma unroll                         // FULL unroll: Bf[kt] compile-time
    for (int c = 0; c < 8; c++){
      __syncthreads();
      if ((c & 1) == 0) write_hf(hregA); else write_hf(hregB);
      if (c == 0){
#pragma unroll
        for (int it = 0; it < 2; it++){
          int idx = it * 512 + tid;
          int row = idx >> 4, c4 = idx & 15;
          *(float4*)(&lds[16384 + row * 256 + c4 * 16]) = xreg[it];
        }
      }
      __syncthreads();
      if (c + 2 < 8){
        if ((c & 1) == 0) load_hto(c + 2, hregA); else load_hto(c + 2, hregB);
      }
#pragma unroll
      for (int kt2 = 0; kt2 < 2; kt2++){
        const int kt = c * 2 + kt2;
        i32x4 Af[2][2];
#pragma unroll
        for (int m = 0; m < 2; m++){
          int hrow = (mh << 5) + (m << 4) + nlo;
          const char* p = &lds[hrow * 256 + ((((kt2 << 2) + quad) ^ (hrow & 7)) << 5)];
          i32x4 r0 = *(const i32x4*)p;          // cols j=0..7 (u16, interleaved b,a)
          i32x4 r1 = *(const i32x4*)(p + 16);   // cols j=8..15
          // split planes: even bytes = b (lo), odd bytes = a (hi)
          i32x4 lo, hi;
          lo[0] = __builtin_amdgcn_perm((unsigned)r0[1], (unsigned)r0[0], 0x06040200u);
          lo[1] = __builtin_amdgcn_perm((unsigned)r0[3], (unsigned)r0[2], 0x06040200u);
          lo[2] = __builtin_amdgcn_perm((unsigned)r1[1], (unsigned)r1[0], 0x06040200u);
          lo[3] = __builtin_amdgcn_perm((unsigned)r1[3], (unsigned)r1[2], 0x06040200u);
          hi[0] = __builtin_amdgcn_perm((unsigned)r0[1], (unsigned)r0[0], 0x07050301u);
          hi[1] = __builtin_amdgcn_perm((unsigned)r0[3], (unsigned)r0[2], 0x07050301u);
          hi[2] = __builtin_amdgcn_perm((unsigned)r1[1], (unsigned)r1[0], 0x07050301u);
          hi[3] = __builtin_amdgcn_perm((unsigned)r1[3], (unsigned)r1[2], 0x07050301u);
          Af[m][0] = hi;
          Af[m][1] = lo;
        }
#pragma unroll
        for (int m = 0; m < 2; m++){
          accH[m] = __builtin_amdgcn_mfma_i32_16x16x64_i8(Af[m][0], Bf[kt][0], accH[m], 0, 0, 0);
          accM[m] = __builtin_amdgcn_mfma_i32_16x16x64_i8(Af[m][0], Bf[kt][1], accM[m], 0, 0, 0);
          accM[m] = __builtin_amdgcn_mfma_i32_16x16x64_i8(Af[m][1], Bf[kt][0], accM[m], 0, 0, 0);
          accL[m] = __builtin_amdgcn_mfma_i32_16x16x64_i8(Af[m][1], Bf[kt][1], accL[m], 0, 0, 0);
        }
      }
    }
    __syncthreads();

    // prefetch next step's xg under the z/elementwise/barrier phases
    if (s + 1 < tc) load_x(s + 1);

    // ---- z = (65536*accH + 256*accM + accL)/(32512*2^17) -> LDS ----
    const float cH = 1.0f / 65024.0f;
    const float cM = 1.0f / 16646144.0f;
    const float cL = 1.0f / 4261412864.0f;
#pragma unroll
    for (int m = 0; m < 2; m++){
#pragma unroll
      for (int r = 0; r < 4; r++){
        float z = (float)accH[m][r] * cH
                + (float)accM[m][r] * cM
                + (float)accL[m][r] * cL;
        int zrow = (mh << 5) + (m << 4) + (quad << 2) + r;
        *(float*)(&lds[32768 + (((zrow * 68) + g * 16 + nlo) << 2)]) = z;
      }
    }
    __syncthreads();

    {
      float ho16[2];   // bf16-packed outputs
      unsigned enc2 = 0;
#pragma unroll
      for (int r = 0; r < 2; r++){
        int col = ecol0 + r;
        float zi = *(const float*)(&lds[32768 + (((erow * 68) + 0  + col) << 2)])
                 + *(const float*)(&lds[16384 + (((erow << 6) + 0  + col) << 2)]);
        float zf = *(const float*)(&lds[32768 + (((erow * 68) + 16 + col) << 2)])
                 + *(const float*)(&lds[16384 + (((erow << 6) + 16 + col) << 2)]);
        float zg = *(const float*)(&lds[32768 + (((erow * 68) + 32 + col) << 2)])
                 + *(const float*)(&lds[16384 + (((erow << 6) + 32 + col) << 2)]);
        float zo = *(const float*)(&lds[32768 + (((erow * 68) + 48 + col) << 2)])
                 + *(const float*)(&lds[16384 + (((erow << 6) + 48 + col) << 2)]);
        float iv = sigm(zi), fv = sigm(zf), ov = sigm(zo), gv = tanhfast(zg);
        float cn = fv * cst[r] + iv * gv;
        float hn = ov * tanhfast(cn);
        bool vld = (t < lenr);
        cst[r] = vld ? cn : cst[r];
        hst[r] = vld ? hn : hst[r];
        ho16[r] = vld ? hn : 0.f;
        int H = (int)rintf(hst[r] * 32512.f);
        H = H > 32512 ? 32512 : (H < -32512 ? -32512 : H);
        int a = (H + 128) >> 8;
        int b_ = H - (a << 8);
        unsigned e = (((unsigned)a & 255u) << 8) | ((unsigned)b_ & 255u);
        enc2 |= e << (r * 16);
      }
      // ohol: 2 adjacent cols -> u32 stores (hi plane, lo plane)
      size_t orow = ((size_t)bglob << tcsh) + s;
      unsigned hi2 = (unsigned)(__float_as_uint(ho16[0]) >> 16)
                   | ((unsigned)(__float_as_uint(ho16[1]) >> 16) << 16);
      unsigned lo2 = (unsigned)bf16lo(ho16[0]) | ((unsigned)bf16lo(ho16[1]) << 16);
      *(unsigned*)(ohol + orow * 2048 + ucol0)        = hi2;
      *(unsigned*)(ohol + orow * 2048 + 1024 + ucol0) = lo2;
      // h(t+1): ONE returning 32-bit atomic exchange (provable release —
      // vmcnt retires only on MALL response; see mbbar).
      unsigned* hp = (unsigned*)(hbb + (((size_t)par2 * 256 + bglob) * 1024 + ucol0) * 2);
      unsigned old = __hip_atomic_exchange(hp, enc2, __ATOMIC_RELAXED,
                                           __HIP_MEMORY_SCOPE_AGENT);
      asm volatile("" :: "v"(old));   // consume result -> returning form
    }
    mbbar(flags, nb, t, wv, lane);
  }

#pragma unroll
  for (int r = 0; r < 2; r++)
    cbuf[(size_t)bglob * 1024 + ucol0 + r] = cst[r];
}

// ---------------------------------------------------------------------------
extern "C" void kernel_launch(void* const* d_in, const int* in_sizes, int n_in,
                              void* d_out, int out_size, void* d_ws, size_t ws_size,
                              hipStream_t stream)
{
  const int*   seq = (const int*)  d_in[0];
  const float* emb = (const float*)d_in[1];
  const float* Wm  = (const float*)d_in[2];
  const float* Um  = (const float*)d_in[3];
  const float* bv  = (const float*)d_in[4];
  const float* fcW = (const float*)d_in[5];
  const float* fcb = (const float*)d_in[6];
  float* out = (float*)d_out;
  char* ws = (char*)d_ws;

  // marker: survives iff no kernel/memset below ever touches d_out
  hipMemsetAsync(d_out, 0x42, 256, stream);   // 64 floats = 48.566

  size_t off = 0;
  unsigned short* wim = (unsigned short*)(ws + off); off += SZ_WIM;
  unsigned short* fcw = (unsigned short*)(ws + off); off += SZ_FCW;
  signed char*    uim = (signed char*)(ws + off);    off += SZ_UIM;
  signed char*    hb  = (signed char*)(ws + off);    off += SZ_HB;
  float*          cb  = (float*)(ws + off);          off += SZ_CB;
  int*            len = (int*)(ws + off);            off += SZ_LEN;
  int*            diag= (int*)(ws + off);            off += SZ_DIAG;
  const size_t fixed = off;

  int tcsh = -1;
  for (int s = 5; s >= 0; s--)
    if (ws && fixed + (5242880ull << s) <= ws_size){ tcsh = s; break; }

  if (tcsh < 0){
    probe_fill<<<(out_size + 255) / 256, 256, 0, stream>>>(
        out, out_size, 1000.0f + (float)(ws_size >> 20));
    return;
  }
  const int tc = 1 << tcsh;

  float*          xgc  = (float*)(ws + fixed);
  unsigned short* ohol = (unsigned short*)(ws + fixed + (size_t)tc * 4194304);

  hipMemsetAsync(diag, 0, SZ_DIAG, stream);   // prog + per-mb barrier flags
  hipMemsetAsync(hb, 0, 524288, stream);      // parity-0 h plane = 0 (enc(0)=0)
  hipMemsetAsync(cb, 0, SZ_CB, stream);       // c state = 0

  int* prog = diag;
  int* barbase = diag + 64;                   // flags: 4 mb x 64 ints, 256B apart

  len_kernel<<<256, 128, 0, stream>>>(seq, len, prog);
  prep_split_img<<<256, 256, 0, stream>>>(Wm, wim, 4096, 256, prog, 2);
  prep_split_img<<<256, 256, 0, stream>>>(fcW, fcw, 1024, 1024, prog, 3);
  prep_uimg<<<256, 256, 0, stream>>>(Um, uim, prog);

  for (int c0 = 0; c0 < 128; c0 += tc){
    gemm_gates<<<dim3((2 * tc) * 32), 256, 0, stream>>>(emb, wim, bv, xgc, seq, c0, tcsh, prog);
    lstm_rec<<<dim3(256), 512, 0, stream>>>(xgc, uim, len, hb, cb, ohol, barbase, prog, c0, tcsh);
    gemm_out<<<dim3((2 * tc) * 8), 256, 0, stream>>>(ohol, fcw, fcb, out, c0, tcsh, prog);
  }

  diag_check<<<1, 64, 0, stream>>>(prog, out);
}

// Round 9
// 3029.393 us; speedup vs baseline: 1.8314x; 1.4338x over previous
//
#include <hip/hip_runtime.h>

typedef short bf16x8 __attribute__((ext_vector_type(8)));   // 8 bf16 in 4 VGPRs
typedef float f32x4  __attribute__((ext_vector_type(4)));
typedef int   i32x4  __attribute__((ext_vector_type(4)));

#define DEVINL __device__ __forceinline__

// ---------------------------------------------------------------------------
// Problem: B=256, T=128, V=10000, E=256, U=1024, 4U=4096, O=1024
// fixed ws ~85 MB + tc*5.25 MB
// ---------------------------------------------------------------------------
static constexpr size_t SZ_WIM  = 4096ull * 512 * 2;   // W img  [4096][hi256|lo256]
static constexpr size_t SZ_FCW  = 1024ull * 2048 * 2;  // fc img [1024][hi1024|lo1024]
static constexpr size_t SZ_UIM  = 8388608;             // U i8 frag img, 2 planes
static constexpr size_t SZ_HH   = 129ull * 524288;     // h history [129 t][256][1024] u16 packed
static constexpr size_t SZ_CB   = 1048576;             // c state [256][1024] f32
static constexpr size_t SZ_LEN  = 4096;
static constexpr size_t SZ_DIAG = 2048;                // prog[0..15] + flags at +256B

DEVINL unsigned short bf16rn(float x){
  unsigned u = __float_as_uint(x);
  unsigned r = (u + 0x7fffu + ((u >> 16) & 1u)) >> 16;
  return (unsigned short)r;
}
DEVINL unsigned short bf16lo(float x){
  unsigned ub = __float_as_uint(x);
  return bf16rn(x - __uint_as_float(ub & 0xffff0000u));
}
DEVINL float sigm(float x){ return 1.f / (1.f + __expf(-x)); }
DEVINL float tanhfast(float x){
  float xc = fminf(15.f, fmaxf(-15.f, x));
  float e = __expf(2.f * xc);
  return (e - 1.f) / (e + 1.f);
}

// ---------------------------------------------------------------------------
__global__ void __launch_bounds__(256) probe_fill(float* __restrict__ out, int n, float v)
{
  int i = blockIdx.x * 256 + threadIdx.x;
  if (i < n) out[i] = (i == 0) ? v : 0.f;
}

// diag: if a stage marker is missing, flood out[0..1023] with 100+stage
__global__ void __launch_bounds__(64) diag_check(const int* __restrict__ prog,
                                                 float* __restrict__ out)
{
  if (threadIdx.x == 0){
    int miss = 0;
    for (int i = 7; i >= 1; i--) if (prog[i] == 0) miss = i;
    if (miss){
      for (int k = 0; k < 1024; k++) out[k] = 100.0f + (float)miss;
    }
  }
}

// ---------------------------------------------------------------------------
__global__ void __launch_bounds__(128) len_kernel(const int* __restrict__ seq,
                                                  int* __restrict__ len,
                                                  int* __restrict__ prog)
{
  int b = blockIdx.x, t = threadIdx.x;
  if (b == 0 && t == 0) prog[1] = 1;
  int pred = (seq[b * 128 + t] != 0) ? 1 : 0;
  unsigned long long m = __ballot(pred);
  __shared__ int cnt[2];
  if ((t & 63) == 0) cnt[t >> 6] = __popcll(m);
  __syncthreads();
  if (t == 0) len[b] = cnt[0] + cnt[1];
}

// ---------------------------------------------------------------------------
// transpose f32 [Ksrc][N] -> bf16 image [N][2*Ksrc] = [hi | lo]
// ---------------------------------------------------------------------------
__global__ void __launch_bounds__(256) prep_split_img(
    const float* __restrict__ S, unsigned short* __restrict__ img, int N, int Ksrc,
    int* __restrict__ prog, int stage)
{
  __shared__ float tile[64][65];
  const int nt = N >> 6;
  const int bn = blockIdx.x % nt, bk = blockIdx.x / nt;
  const int tid = threadIdx.x;
  if (blockIdx.x == 0 && tid == 0) prog[stage] = 1;
  {
    const int kk = tid >> 6, n = tid & 63;
#pragma unroll 4
    for (int i = 0; i < 16; i++){
      int k = i * 4 + kk;
      tile[k][n] = S[(size_t)((bk << 6) + k) * N + (bn << 6) + n];
    }
  }
  __syncthreads();
  {
    const int n4 = tid >> 6, k = tid & 63;
#pragma unroll 4
    for (int i = 0; i < 16; i++){
      int n = i * 4 + n4;
      float v = tile[k][n];
      size_t rowoff = (size_t)((bn << 6) + n) * (2 * Ksrc) + (bk << 6) + k;
      img[rowoff] = (unsigned short)(__float_as_uint(v) >> 16);
      img[rowoff + Ksrc] = bf16lo(v);
    }
  }
}

// ---------------------------------------------------------------------------
// U (f32 [1024][4096]) -> i8 fragment image, 2 planes (hi,lo of 16-bit *2^17)
// ---------------------------------------------------------------------------
__global__ void __launch_bounds__(256) prep_uimg(const float* __restrict__ U,
                                                 signed char* __restrict__ img,
                                                 int* __restrict__ prog)
{
  const int bid = blockIdx.x;
  const int nb = bid >> 2, nt4 = bid & 3;
  const int tid = threadIdx.x;
  if (bid == 0 && tid == 0) prog[4] = 1;
  __shared__ signed char lc[16384], ldq[16384];  // [k 1024][16 cols]
  const int colbase = nt4 * 1024 + (nb << 4);
  const int kk = tid >> 4, cc = tid & 15;
#pragma unroll 4
  for (int it = 0; it < 64; it++){
    int k = it * 16 + kk;
    float v = U[(size_t)k * 4096 + colbase + cc];
    int q = (int)rintf(v * 131072.f);            // U * 2^17
    q = q > 32639 ? 32639 : (q < -32639 ? -32639 : q);
    int a = (q + 128) >> 8;
    int d = q - (a << 8);
    lc[(k << 4) + cc]  = (signed char)a;
    ldq[(k << 4) + cc] = (signed char)d;
  }
  __syncthreads();
#pragma unroll
  for (int rep = 0; rep < 4; rep++){
    int idx = rep * 256 + tid;                   // 0..1023
    int kt = idx >> 6, lane = idx & 63;
    int n = lane & 15, quad = lane >> 4;
    union { signed char b[16]; i32x4 v; } cb_, db_;
#pragma unroll
    for (int j = 0; j < 16; j++){
      int k = (kt << 6) + (quad << 4) + j;
      cb_.b[j] = lc[(k << 4) + n];
      db_.b[j] = ldq[(k << 4) + n];
    }
    size_t base = (size_t)((((nb << 2) + nt4) * 16 + kt) * 2) * 1024;
    *(i32x4*)(img + base + (size_t)lane * 16)        = cb_.v;
    *(i32x4*)(img + base + 1024 + (size_t)lane * 16) = db_.v;
  }
}

// ---------------------------------------------------------------------------
// gates GEMM: xg[256*tc][4096] = token-gathered emb x Wimg + bias (3-product).
// ---------------------------------------------------------------------------
__global__ void __launch_bounds__(256) gemm_gates(
    const float* __restrict__ emb, const unsigned short* __restrict__ Bimg,
    const float* __restrict__ bias, float* __restrict__ D,
    const int* __restrict__ seq, int c0, int tcsh, int* __restrict__ prog)
{
  __shared__ __align__(16) char lds[16384];   // A 8KB | B 8KB
  __shared__ int stok[128];
  const int tid = threadIdx.x, lane = tid & 63, wv = tid >> 6;
  const int quad = lane >> 4, nlo = lane & 15;
  const int wm = wv & 1, wn = wv >> 1;
  const int rowbase = (blockIdx.x >> 5) << 7;   // 32 col-tiles
  const int colbase = (blockIdx.x & 31) << 7;
  const int tcm1 = (1 << tcsh) - 1;
  if (blockIdx.x == 0 && tid == 0) prog[5] = 1;
  if (tid < 128){
    int r = rowbase + tid;
    stok[tid] = seq[((r >> tcsh) << 7) + c0 + (r & tcm1)];
  }
  __syncthreads();

  f32x4 acc[4][4];
#pragma unroll
  for (int i = 0; i < 4; i++)
#pragma unroll
    for (int j = 0; j < 4; j++) acc[i][j] = (f32x4){0.f, 0.f, 0.f, 0.f};

  float4 va[2][2]; int4 vb[2];
  auto loadAB = [&](int c){
    int k0 = c * 32;
    int seg = (k0 >= 512) ? 2 : (k0 >= 256 ? 1 : 0);
    int acol = k0 - seg * 256;
    int boff = (seg == 2 ? 256 : 0) + acol;
#pragma unroll
    for (int p = 0; p < 2; p++){
      int gidx = p * 256 + tid;
      int row = gidx >> 2, sg = gidx & 3;
      const float* ap = emb + (size_t)stok[row] * 256 + acol + sg * 8;
      va[p][0] = *(const float4*)ap;
      va[p][1] = *(const float4*)(ap + 4);
      vb[p] = *(const int4*)(Bimg + (size_t)(colbase + row) * 512 + boff + sg * 8);
    }
  };
  auto writeAB = [&](int c){
    int k0 = c * 32;
    int seg = (k0 >= 512) ? 2 : (k0 >= 256 ? 1 : 0);
#pragma unroll
    for (int p = 0; p < 2; p++){
      int gidx = p * 256 + tid;
      int row = gidx >> 2, sg = gidx & 3;
      float vv[8] = {va[p][0].x, va[p][0].y, va[p][0].z, va[p][0].w,
                     va[p][1].x, va[p][1].y, va[p][1].z, va[p][1].w};
      union { unsigned short s[8]; int4 q; } pk;
      if (seg == 1){
#pragma unroll
        for (int j = 0; j < 8; j++) pk.s[j] = bf16lo(vv[j]);
      } else {
#pragma unroll
        for (int j = 0; j < 8; j++) pk.s[j] = (unsigned short)(__float_as_uint(vv[j]) >> 16);
      }
      int sw = (sg ^ ((row >> 1) & 3)) << 4;
      *(int4*)(&lds[row * 64 + sw]) = pk.q;
      *(int4*)(&lds[8192 + row * 64 + sw]) = vb[p];
    }
  };

  loadAB(0);
#pragma unroll 2
  for (int c = 0; c < 24; c++){
    __syncthreads();
    writeAB(c);
    __syncthreads();
    if (c + 1 < 24) loadAB(c + 1);
    bf16x8 af[4], bfr[4];
#pragma unroll
    for (int mt = 0; mt < 4; mt++){
      int r = wm * 64 + mt * 16 + nlo;
      af[mt] = *(const bf16x8*)(&lds[r * 64 + ((quad ^ ((r >> 1) & 3)) << 4)]);
    }
#pragma unroll
    for (int nt = 0; nt < 4; nt++){
      int r = wn * 64 + nt * 16 + nlo;
      bfr[nt] = *(const bf16x8*)(&lds[8192 + r * 64 + ((quad ^ ((r >> 1) & 3)) << 4)]);
    }
#pragma unroll
    for (int mt = 0; mt < 4; mt++)
#pragma unroll
      for (int nt = 0; nt < 4; nt++)
        acc[mt][nt] = __builtin_amdgcn_mfma_f32_16x16x32_bf16(af[mt], bfr[nt], acc[mt][nt], 0, 0, 0);
  }

  float bs[4];
#pragma unroll
  for (int nt = 0; nt < 4; nt++) bs[nt] = bias[colbase + wn * 64 + nt * 16 + nlo];
#pragma unroll
  for (int mt = 0; mt < 4; mt++)
#pragma unroll
    for (int nt = 0; nt < 4; nt++){
      int col = colbase + wn * 64 + nt * 16 + nlo;
#pragma unroll
      for (int r = 0; r < 4; r++){
        int row = rowbase + wm * 64 + mt * 16 + quad * 4 + r;
        D[(size_t)row * 4096 + col] = acc[mt][nt][r] + bs[nt];
      }
    }
}

// ---------------------------------------------------------------------------
// output GEMM: out[b*128+c0+s][1024] = ohol x fcw + fcb (3-product, K'=3072)
// ---------------------------------------------------------------------------
__global__ void __launch_bounds__(256) gemm_out(
    const unsigned short* __restrict__ ohol, const unsigned short* __restrict__ Bimg,
    const float* __restrict__ bias, float* __restrict__ D,
    int c0, int tcsh, int* __restrict__ prog)
{
  __shared__ __align__(16) char lds[16384];
  const int tid = threadIdx.x, lane = tid & 63, wv = tid >> 6;
  const int quad = lane >> 4, nlo = lane & 15;
  const int wm = wv & 1, wn = wv >> 1;
  const int rowbase = (blockIdx.x >> 3) << 7;   // 8 col-tiles
  const int colbase = (blockIdx.x & 7) << 7;
  const int tcm1 = (1 << tcsh) - 1;
  if (blockIdx.x == 0 && tid == 0) prog[7] = 1;

  f32x4 acc[4][4];
#pragma unroll
  for (int i = 0; i < 4; i++)
#pragma unroll
    for (int j = 0; j < 4; j++) acc[i][j] = (f32x4){0.f, 0.f, 0.f, 0.f};

  int4 va[2], vb[2];
  auto loadAB = [&](int c){
    int k0 = c * 32;
    int seg = (k0 >= 2048) ? 2 : (k0 >= 1024 ? 1 : 0);
    int acol = k0 - seg * 1024;
    int aoff = (seg == 1 ? 1024 : 0) + acol;
    int boff = (seg == 2 ? 1024 : 0) + acol;
#pragma unroll
    for (int p = 0; p < 2; p++){
      int gidx = p * 256 + tid;
      int row = gidx >> 2, sg = gidx & 3;
      va[p] = *(const int4*)(ohol + (size_t)(rowbase + row) * 2048 + aoff + sg * 8);
      vb[p] = *(const int4*)(Bimg + (size_t)(colbase + row) * 2048 + boff + sg * 8);
    }
  };
  auto writeAB = [&](){
#pragma unroll
    for (int p = 0; p < 2; p++){
      int gidx = p * 256 + tid;
      int row = gidx >> 2, sg = gidx & 3;
      int sw = (sg ^ ((row >> 1) & 3)) << 4;
      *(int4*)(&lds[row * 64 + sw]) = va[p];
      *(int4*)(&lds[8192 + row * 64 + sw]) = vb[p];
    }
  };

  loadAB(0);
#pragma unroll 2
  for (int c = 0; c < 96; c++){
    __syncthreads();
    writeAB();
    __syncthreads();
    if (c + 1 < 96) loadAB(c + 1);
    bf16x8 af[4], bfr[4];
#pragma unroll
    for (int mt = 0; mt < 4; mt++){
      int r = wm * 64 + mt * 16 + nlo;
      af[mt] = *(const bf16x8*)(&lds[r * 64 + ((quad ^ ((r >> 1) & 3)) << 4)]);
    }
#pragma unroll
    for (int nt = 0; nt < 4; nt++){
      int r = wn * 64 + nt * 16 + nlo;
      bfr[nt] = *(const bf16x8*)(&lds[8192 + r * 64 + ((quad ^ ((r >> 1) & 3)) << 4)]);
    }
#pragma unroll
    for (int mt = 0; mt < 4; mt++)
#pragma unroll
      for (int nt = 0; nt < 4; nt++)
        acc[mt][nt] = __builtin_amdgcn_mfma_f32_16x16x32_bf16(af[mt], bfr[nt], acc[mt][nt], 0, 0, 0);
  }

  float bs[4];
#pragma unroll
  for (int nt = 0; nt < 4; nt++) bs[nt] = bias[colbase + wn * 64 + nt * 16 + nlo];
#pragma unroll
  for (int mt = 0; mt < 4; mt++)
#pragma unroll
    for (int nt = 0; nt < 4; nt++){
      int col = colbase + wn * 64 + nt * 16 + nlo;
#pragma unroll
      for (int r = 0; r < 4; r++){
        int row = rowbase + wm * 64 + mt * 16 + quad * 4 + r;
        int drow = ((row >> tcsh) << 7) + c0 + (row & tcm1);
        D[(size_t)drow * 1024 + col] = acc[mt][nt][r] + bs[nt];
      }
    }
}

// ---------------------------------------------------------------------------
// per-mb-group FLAG-ARRAY barrier (64 WGs), ZERO cache maintenance:
//   Writer side (R8-proven): h(t+1) written via RETURNING agent-scope 32-bit
//   atomic_exchange (result consumed) -> executes at the MALL; vmcnt retires
//   on response -> after __syncthreads() all h-words are AT the coherence
//   point.  The relaxed flag store can then never outrun the data.
//   Reader side (R3-proven): h addresses are LAUNCH-FRESH (hh[t] history) ->
//   no L1/L2 anywhere can hold a stale copy -> plain cached loads are safe
//   with NO acquire fence / NO buffer_inv.  First reader per XCD fills L2;
//   the other ~31 resident WGs hit L2.  L2 stays warm across steps (xg too).
//   This deletes the 32-per-XCD-per-step L2 invalidates (R5-R8's hidden
//   ~13us/step) and restores L2 sharing of the h broadcast.
//   - wait: wave 0 polls all 64 flags IN PARALLEL (lane i -> flag[i]).
//   - workgroup acquire fence = compiler-only ordering (no cache ops).
// flags[mb][0..63]: 256B per group, groups 256B apart -> no false sharing.
// ---------------------------------------------------------------------------
DEVINL void mbbar(int* flags, int nb, int t, int wv, int lane){
  __syncthreads();   // vmcnt(0) per wave: all h-exchanges RESPONDED (at MALL)
  if (wv == 0){
    if (lane == 0)
      __hip_atomic_store(&flags[nb], t + 1, __ATOMIC_RELAXED, __HIP_MEMORY_SCOPE_AGENT);
    const int tgt = t + 1;
    for (;;){
      int v = __hip_atomic_load(&flags[lane], __ATOMIC_RELAXED, __HIP_MEMORY_SCOPE_AGENT);
      if (__ballot(v >= tgt) == ~0ull) break;
      __builtin_amdgcn_s_sleep(1);
    }
    __builtin_amdgcn_fence(__ATOMIC_ACQUIRE, "workgroup");  // compiler ordering only
  }
  __syncthreads();
}

// ---------------------------------------------------------------------------
// persistent LSTM recurrence, tc steps/launch.  256 WGs x 512 thr = 4 mb x 64 nb.
// 8 waves/WG = mh(2) x gate(4); per-lane U-frags Bf[16][2] = 128 VGPRs,
// c-loop FULLY UNROLLED (compile-time Bf indices; R5 proven).
// R9: h history hh[t] packed u16 (a<<8|b), fresh slot per step (no reader
// fence — see mbbar); writer = one returning u32 atomic_exchange per thread.
// LDS h tile back to R5's two-plane 16B-granule layout (2.1M bank conflicts,
// vs R8's packed layout at 31.5M); hi/lo split done at STAGING time with
// 8 v_perm per thread per c-iter (zero perms in the MFMA loop).
// 2-deep h-load pipeline (load c+2 during iter c).
// ---------------------------------------------------------------------------
__global__ void __launch_bounds__(512, 2) lstm_rec(
    const float* __restrict__ xg,        // [256*tc][4096] f32, row = b*tc+s
    const signed char* __restrict__ uimg,
    const int* __restrict__ len,
    signed char* __restrict__ hh,        // [129 t][256][1024] u16 packed history
    float* __restrict__ cbuf,            // [256][1024] f32
    unsigned short* __restrict__ ohol,   // [256*tc][hi1024|lo1024]
    int* __restrict__ barbase,           // flags[mb] at barbase + mb*64 ints
    int* __restrict__ prog,
    int c0, int tcsh)
{
  // LDS: [0,16384) h tile (2 pl x 64 r x 128B, 16B-granule XOR swizzle);
  //      [16384,32768) xg f32 [64][64]; [32768,50176) z f32 [64][68]
  __shared__ __align__(16) char lds[50176];
  const int tc = 1 << tcsh;
  const int wg = blockIdx.x, mb = wg >> 6, nb = wg & 63;
  const int tid = threadIdx.x, lane = tid & 63, wv = tid >> 6;  // wv 0..7
  const int quad = lane >> 4, nlo = lane & 15;
  const int mh = wv & 1, g = wv >> 1;                           // gate 0..3
  int* flags = barbase + (mb << 6);
  if (wg == 0 && tid == 0) prog[6] = 1;

  const unsigned short* hh2 = (const unsigned short*)hh;

  // ---- U fragments -> registers: gate g, u-block nb, 16 kt x 2 planes ----
  i32x4 Bf[16][2];
#pragma unroll
  for (int kt = 0; kt < 16; kt++)
#pragma unroll
    for (int pl = 0; pl < 2; pl++){
      size_t off = (size_t)((((nb << 2) + g) * 16 + kt) * 2 + pl);
      off = (off * 64 + lane) << 4;
      Bf[kt][pl] = *(const i32x4*)(uimg + off);
    }

  // ---- elementwise mapping: thread = (1 row x 2 adjacent cols) ----
  const int erow = tid >> 3;            // 0..63 local row
  const int ecp  = tid & 7;             // col-pair index
  const int ecol0 = ecp << 1;           // local col (even)
  const int ucol0 = (nb << 4) + ecol0;  // global u col (even)
  const int bglob = (mb << 6) + erow;
  const int lenr = len[bglob];
  float cst[2], hst[2];
#pragma unroll
  for (int r = 0; r < 2; r++){
    cst[r] = cbuf[(size_t)bglob * 1024 + ucol0 + r];
    unsigned short e = hh2[(size_t)c0 * 262144 + (size_t)bglob * 1024 + ucol0 + r];
    int a = (signed char)(e >> 8), b_ = (signed char)(e & 255);
    hst[r] = (float)(a * 256 + b_) * (1.0f / 32512.0f);
  }

  // xg prefetch: issued before mbbar so HBM latency hides under the spin.
  float4 xreg[2];
  auto load_x = [&](int s){
#pragma unroll
    for (int it = 0; it < 2; it++){
      int idx = it * 512 + tid;
      int row = idx >> 4, c4 = idx & 15;
      xreg[it] = *(const float4*)(xg + (size_t)((((mb << 6) + row) << tcsh) + s) * 4096
                                  + (c4 >> 2) * 1024 + (nb << 4) + ((c4 & 3) << 2));
    }
  };
  load_x(0);

  // h staging mapping: thread = (1 row x one 32B packed block of 8)
  const int hrw = tid >> 3, hsub = tid & 7;

#pragma unroll 1
  for (int s = 0; s < tc; s++){
    const int t = c0 + s;
    // input h of step t lives at slot t (launch-fresh addresses -> plain loads)
    const signed char* hsrc = hh + (size_t)t * 524288 + (size_t)(mb << 6) * 2048;

    i32x4 accH[2], accM[2], accL[2];
#pragma unroll
    for (int m = 0; m < 2; m++){
      accH[m] = (i32x4){0,0,0,0};
      accM[m] = (i32x4){0,0,0,0};
      accL[m] = (i32x4){0,0,0,0};
    }

    int4 hregA[2], hregB[2];
    auto load_hto = [&](int c, int4* dst){
      const signed char* p = hsrc + (size_t)hrw * 2048 + c * 256 + hsub * 32;
      dst[0] = *(const int4*)p;
      dst[1] = *(const int4*)(p + 16);
    };
    // split packed u16 block (16 cols) -> hi plane 16B + lo plane 16B, write
    // with the R5 16B-granule swizzle (conflict behavior = R5's 2.1M).
    auto write_hf = [&](const int4* src){
      unsigned r0 = (unsigned)src[0].x, r1 = (unsigned)src[0].y;
      unsigned r2 = (unsigned)src[0].z, r3 = (unsigned)src[0].w;
      unsigned r4 = (unsigned)src[1].x, r5 = (unsigned)src[1].y;
      unsigned r6 = (unsigned)src[1].z, r7 = (unsigned)src[1].w;
      i32x4 lo, hi;
      lo[0] = __builtin_amdgcn_perm(r1, r0, 0x06040200u);
      lo[1] = __builtin_amdgcn_perm(r3, r2, 0x06040200u);
      lo[2] = __builtin_amdgcn_perm(r5, r4, 0x06040200u);
      lo[3] = __builtin_amdgcn_perm(r7, r6, 0x06040200u);
      hi[0] = __builtin_amdgcn_perm(r1, r0, 0x07050301u);
      hi[1] = __builtin_amdgcn_perm(r3, r2, 0x07050301u);
      hi[2] = __builtin_amdgcn_perm(r5, r4, 0x07050301u);
      hi[3] = __builtin_amdgcn_perm(r7, r6, 0x07050301u);
      int sw = (hsub ^ (hrw & 7)) << 4;
      *(i32x4*)(&lds[hrw * 128 + sw])        = hi;   // plane 0 = hi bytes (a)
      *(i32x4*)(&lds[8192 + hrw * 128 + sw]) = lo;   // plane 1 = lo bytes (b)
    };

    load_hto(0, hregA);
    load_hto(1, hregB);

#pragma unroll                         // FULL unroll: Bf[kt] compile-time
    for (int c = 0; c < 8; c++){
      __syncthreads();
      if ((c & 1) == 0) write_hf(hregA); else write_hf(hregB);
      if (c == 0){
#pragma unroll
        for (int it = 0; it < 2; it++){
          int idx = it * 512 + tid;
          int row = idx >> 4, c4 = idx & 15;
          *(float4*)(&lds[16384 + row * 256 + c4 * 16]) = xreg[it];
        }
      }
      __syncthreads();
      if (c + 2 < 8){
        if ((c & 1) == 0) load_hto(c + 2, hregA); else load_hto(c + 2, hregB);
      }
#pragma unroll
      for (int kt2 = 0; kt2 < 2; kt2++){
        const int kt = c * 2 + kt2;
        i32x4 Af[2][2];
#pragma unroll
        for (int m = 0; m < 2; m++){
          int hrow = (mh << 5) + (m << 4) + nlo;
          int sgl = ((kt2 << 2) + quad) ^ (hrow & 7);
          Af[m][0] = *(const i32x4*)(&lds[hrow * 128 + (sgl << 4)]);
          Af[m][1] = *(const i32x4*)(&lds[8192 + hrow * 128 + (sgl << 4)]);
        }
#pragma unroll
        for (int m = 0; m < 2; m++){
          accH[m] = __builtin_amdgcn_mfma_i32_16x16x64_i8(Af[m][0], Bf[kt][0], accH[m], 0, 0, 0);
          accM[m] = __builtin_amdgcn_mfma_i32_16x16x64_i8(Af[m][0], Bf[kt][1], accM[m], 0, 0, 0);
          accM[m] = __builtin_amdgcn_mfma_i32_16x16x64_i8(Af[m][1], Bf[kt][0], accM[m], 0, 0, 0);
          accL[m] = __builtin_amdgcn_mfma_i32_16x16x64_i8(Af[m][1], Bf[kt][1], accL[m], 0, 0, 0);
        }
      }
    }
    __syncthreads();

    // prefetch next step's xg under the z/elementwise/barrier phases
    if (s + 1 < tc) load_x(s + 1);

    // ---- z = (65536*accH + 256*accM + accL)/(32512*2^17) -> LDS ----
    const float cH = 1.0f / 65024.0f;
    const float cM = 1.0f / 16646144.0f;
    const float cL = 1.0f / 4261412864.0f;
#pragma unroll
    for (int m = 0; m < 2; m++){
#pragma unroll
      for (int r = 0; r < 4; r++){
        float z = (float)accH[m][r] * cH
                + (float)accM[m][r] * cM
                + (float)accL[m][r] * cL;
        int zrow = (mh << 5) + (m << 4) + (quad << 2) + r;
        *(float*)(&lds[32768 + (((zrow * 68) + g * 16 + nlo) << 2)]) = z;
      }
    }
    __syncthreads();

    {
      float ho16[2];
      unsigned enc2 = 0;
#pragma unroll
      for (int r = 0; r < 2; r++){
        int col = ecol0 + r;
        float zi = *(const float*)(&lds[32768 + (((erow * 68) + 0  + col) << 2)])
                 + *(const float*)(&lds[16384 + (((erow << 6) + 0  + col) << 2)]);
        float zf = *(const float*)(&lds[32768 + (((erow * 68) + 16 + col) << 2)])
                 + *(const float*)(&lds[16384 + (((erow << 6) + 16 + col) << 2)]);
        float zg = *(const float*)(&lds[32768 + (((erow * 68) + 32 + col) << 2)])
                 + *(const float*)(&lds[16384 + (((erow << 6) + 32 + col) << 2)]);
        float zo = *(const float*)(&lds[32768 + (((erow * 68) + 48 + col) << 2)])
                 + *(const float*)(&lds[16384 + (((erow << 6) + 48 + col) << 2)]);
        float iv = sigm(zi), fv = sigm(zf), ov = sigm(zo), gv = tanhfast(zg);
        float cn = fv * cst[r] + iv * gv;
        float hn = ov * tanhfast(cn);
        bool vld = (t < lenr);
        cst[r] = vld ? cn : cst[r];
        hst[r] = vld ? hn : hst[r];
        ho16[r] = vld ? hn : 0.f;
        int H = (int)rintf(hst[r] * 32512.f);
        H = H > 32512 ? 32512 : (H < -32512 ? -32512 : H);
        int a = (H + 128) >> 8;
        int b_ = H - (a << 8);
        unsigned e = (((unsigned)a & 255u) << 8) | ((unsigned)b_ & 255u);
        enc2 |= e << (r * 16);
      }
      // ohol: 2 adjacent cols -> u32 stores (hi plane, lo plane)
      size_t orow = ((size_t)bglob << tcsh) + s;
      unsigned hi2 = (unsigned)(__float_as_uint(ho16[0]) >> 16)
                   | ((unsigned)(__float_as_uint(ho16[1]) >> 16) << 16);
      unsigned lo2 = (unsigned)bf16lo(ho16[0]) | ((unsigned)bf16lo(ho16[1]) << 16);
      *(unsigned*)(ohol + orow * 2048 + ucol0)        = hi2;
      *(unsigned*)(ohol + orow * 2048 + 1024 + ucol0) = lo2;
      // h(t+1) -> FRESH slot: ONE returning 32-bit atomic exchange (provable
      // release — vmcnt retires only on MALL response; see mbbar).
      unsigned* hp = (unsigned*)(hh + (size_t)(t + 1) * 524288
                                 + ((size_t)bglob * 1024 + ucol0) * 2);
      unsigned old = __hip_atomic_exchange(hp, enc2, __ATOMIC_RELAXED,
                                           __HIP_MEMORY_SCOPE_AGENT);
      asm volatile("" :: "v"(old));   // consume result -> returning form
    }
    mbbar(flags, nb, t, wv, lane);
  }

#pragma unroll
  for (int r = 0; r < 2; r++)
    cbuf[(size_t)bglob * 1024 + ucol0 + r] = cst[r];
}

// ---------------------------------------------------------------------------
extern "C" void kernel_launch(void* const* d_in, const int* in_sizes, int n_in,
                              void* d_out, int out_size, void* d_ws, size_t ws_size,
                              hipStream_t stream)
{
  const int*   seq = (const int*)  d_in[0];
  const float* emb = (const float*)d_in[1];
  const float* Wm  = (const float*)d_in[2];
  const float* Um  = (const float*)d_in[3];
  const float* bv  = (const float*)d_in[4];
  const float* fcW = (const float*)d_in[5];
  const float* fcb = (const float*)d_in[6];
  float* out = (float*)d_out;
  char* ws = (char*)d_ws;

  // marker: survives iff no kernel/memset below ever touches d_out
  hipMemsetAsync(d_out, 0x42, 256, stream);   // 64 floats = 48.566

  size_t off = 0;
  unsigned short* wim = (unsigned short*)(ws + off); off += SZ_WIM;
  unsigned short* fcw = (unsigned short*)(ws + off); off += SZ_FCW;
  signed char*    uim = (signed char*)(ws + off);    off += SZ_UIM;
  signed char*    hh  = (signed char*)(ws + off);    off += SZ_HH;
  float*          cb  = (float*)(ws + off);          off += SZ_CB;
  int*            len = (int*)(ws + off);            off += SZ_LEN;
  int*            diag= (int*)(ws + off);            off += SZ_DIAG;
  const size_t fixed = off;

  int tcsh = -1;
  for (int s = 5; s >= 0; s--)
    if (ws && fixed + (5242880ull << s) <= ws_size){ tcsh = s; break; }

  if (tcsh < 0){
    probe_fill<<<(out_size + 255) / 256, 256, 0, stream>>>(
        out, out_size, 1000.0f + (float)(ws_size >> 20));
    return;
  }
  const int tc = 1 << tcsh;

  float*          xgc  = (float*)(ws + fixed);
  unsigned short* ohol = (unsigned short*)(ws + fixed + (size_t)tc * 4194304);

  hipMemsetAsync(diag, 0, SZ_DIAG, stream);   // prog + per-mb barrier flags
  hipMemsetAsync(hh, 0, 524288, stream);      // h history slot 0 = 0 (enc(0)=0)
  hipMemsetAsync(cb, 0, SZ_CB, stream);       // c state = 0

  int* prog = diag;
  int* barbase = diag + 64;                   // flags: 4 mb x 64 ints, 256B apart

  len_kernel<<<256, 128, 0, stream>>>(seq, len, prog);
  prep_split_img<<<256, 256, 0, stream>>>(Wm, wim, 4096, 256, prog, 2);
  prep_split_img<<<256, 256, 0, stream>>>(fcW, fcw, 1024, 1024, prog, 3);
  prep_uimg<<<256, 256, 0, stream>>>(Um, uim, prog);

  for (int c0 = 0; c0 < 128; c0 += tc){
    gemm_gates<<<dim3((2 * tc) * 32), 256, 0, stream>>>(emb, wim, bv, xgc, seq, c0, tcsh, prog);
    lstm_rec<<<dim3(256), 512, 0, stream>>>(xgc, uim, len, hh, cb, ohol, barbase, prog, c0, tcsh);
    gemm_out<<<dim3((2 * tc) * 8), 256, 0, stream>>>(ohol, fcw, fcb, out, c0, tcsh, prog);
  }

  diag_check<<<1, 64, 0, stream>>>(prog, out);
}

// Round 10
// 2116.609 us; speedup vs baseline: 2.6212x; 1.4312x over previous
//
#include <hip/hip_runtime.h>

typedef short bf16x8 __attribute__((ext_vector_type(8)));   // 8 bf16 in 4 VGPRs
typedef float f32x4  __attribute__((ext_vector_type(4)));
typedef int   i32x4  __attribute__((ext_vector_type(4)));

#define DEVINL __device__ __forceinline__

// ---------------------------------------------------------------------------
// Problem: B=256, T=128, V=10000, E=256, U=1024, 4U=4096, O=1024
// fixed ws ~45 MB + tc*5.25 MB
// ---------------------------------------------------------------------------
static constexpr size_t SZ_WIM  = 4096ull * 512 * 2;   // W img  [4096][hi256|lo256]
static constexpr size_t SZ_FCW  = 1024ull * 2048 * 2;  // fc img [1024][hi1024|lo1024]
static constexpr size_t SZ_UIM  = 8388608;             // U i8 frag img, 2 planes
static constexpr size_t SZ_EBI  = 10000ull * 512 * 2;  // emb img [10000][hi256|lo256]
static constexpr size_t SZ_HH   = 33ull * 524288;      // h history [33 slot][256][1024] u16
static constexpr size_t SZ_CB   = 1048576;             // c state [256][1024] f32
static constexpr size_t SZ_LEN  = 4096;
static constexpr size_t SZ_DIAG = 2048;                // prog[0..15] + flags at +256B

DEVINL unsigned short bf16rn(float x){
  unsigned u = __float_as_uint(x);
  unsigned r = (u + 0x7fffu + ((u >> 16) & 1u)) >> 16;
  return (unsigned short)r;
}
DEVINL unsigned short bf16lo(float x){
  unsigned ub = __float_as_uint(x);
  return bf16rn(x - __uint_as_float(ub & 0xffff0000u));
}
DEVINL float sigm(float x){ return 1.f / (1.f + __expf(-x)); }
DEVINL float tanhfast(float x){
  float xc = fminf(15.f, fmaxf(-15.f, x));
  float e = __expf(2.f * xc);
  return (e - 1.f) / (e + 1.f);
}
// async 16B global->LDS DMA; LDS dest = wave-uniform base + lane*16,
// global source is PER-LANE (gather/pre-swizzle legal).  size must be literal.
DEVINL void gl_lds16(const void* g, void* l){
  __builtin_amdgcn_global_load_lds(
      (const __attribute__((address_space(1))) unsigned*)g,
      (__attribute__((address_space(3))) unsigned*)l, 16, 0, 0);
}
DEVINL int hslot(int t){ return t % 33; }   // 33 slots: distinct within a launch

// ---------------------------------------------------------------------------
__global__ void __launch_bounds__(256) probe_fill(float* __restrict__ out, int n, float v)
{
  int i = blockIdx.x * 256 + threadIdx.x;
  if (i < n) out[i] = (i == 0) ? v : 0.f;
}

// diag: if a stage marker is missing, flood out[0..1023] with 100+stage
__global__ void __launch_bounds__(64) diag_check(const int* __restrict__ prog,
                                                 float* __restrict__ out)
{
  if (threadIdx.x == 0){
    int miss = 0;
    for (int i = 7; i >= 1; i--) if (prog[i] == 0) miss = i;
    if (miss){
      for (int k = 0; k < 1024; k++) out[k] = 100.0f + (float)miss;
    }
  }
}

// ---------------------------------------------------------------------------
__global__ void __launch_bounds__(128) len_kernel(const int* __restrict__ seq,
                                                  int* __restrict__ len,
                                                  int* __restrict__ prog)
{
  int b = blockIdx.x, t = threadIdx.x;
  if (b == 0 && t == 0) prog[1] = 1;
  int pred = (seq[b * 128 + t] != 0) ? 1 : 0;
  unsigned long long m = __ballot(pred);
  __shared__ int cnt[2];
  if ((t & 63) == 0) cnt[t >> 6] = __popcll(m);
  __syncthreads();
  if (t == 0) len[b] = cnt[0] + cnt[1];
}

// ---------------------------------------------------------------------------
// transpose f32 [Ksrc][N] -> bf16 image [N][2*Ksrc] = [hi | lo]
// ---------------------------------------------------------------------------
__global__ void __launch_bounds__(256) prep_split_img(
    const float* __restrict__ S, unsigned short* __restrict__ img, int N, int Ksrc,
    int* __restrict__ prog, int stage)
{
  __shared__ float tile[64][65];
  const int nt = N >> 6;
  const int bn = blockIdx.x % nt, bk = blockIdx.x / nt;
  const int tid = threadIdx.x;
  if (blockIdx.x == 0 && tid == 0) prog[stage] = 1;
  {
    const int kk = tid >> 6, n = tid & 63;
#pragma unroll 4
    for (int i = 0; i < 16; i++){
      int k = i * 4 + kk;
      tile[k][n] = S[(size_t)((bk << 6) + k) * N + (bn << 6) + n];
    }
  }
  __syncthreads();
  {
    const int n4 = tid >> 6, k = tid & 63;
#pragma unroll 4
    for (int i = 0; i < 16; i++){
      int n = i * 4 + n4;
      float v = tile[k][n];
      size_t rowoff = (size_t)((bn << 6) + n) * (2 * Ksrc) + (bk << 6) + k;
      img[rowoff] = (unsigned short)(__float_as_uint(v) >> 16);
      img[rowoff + Ksrc] = bf16lo(v);
    }
  }
}

// ---------------------------------------------------------------------------
// emb f32 [10000][256] -> u16 image [10000][hi256|lo256] (row-major, no transpose)
// ---------------------------------------------------------------------------
__global__ void __launch_bounds__(256) prep_emb_img(const float* __restrict__ emb,
                                                    unsigned short* __restrict__ img)
{
  const int v = blockIdx.x, t = threadIdx.x;
  float x = emb[(size_t)v * 256 + t];
  img[(size_t)v * 512 + t]       = (unsigned short)(__float_as_uint(x) >> 16);
  img[(size_t)v * 512 + 256 + t] = bf16lo(x);
}

// ---------------------------------------------------------------------------
// U (f32 [1024][4096]) -> i8 fragment image, 2 planes (hi,lo of 16-bit *2^17)
// ---------------------------------------------------------------------------
__global__ void __launch_bounds__(256) prep_uimg(const float* __restrict__ U,
                                                 signed char* __restrict__ img,
                                                 int* __restrict__ prog)
{
  const int bid = blockIdx.x;
  const int nb = bid >> 2, nt4 = bid & 3;
  const int tid = threadIdx.x;
  if (bid == 0 && tid == 0) prog[4] = 1;
  __shared__ signed char lc[16384], ldq[16384];  // [k 1024][16 cols]
  const int colbase = nt4 * 1024 + (nb << 4);
  const int kk = tid >> 4, cc = tid & 15;
#pragma unroll 4
  for (int it = 0; it < 64; it++){
    int k = it * 16 + kk;
    float v = U[(size_t)k * 4096 + colbase + cc];
    int q = (int)rintf(v * 131072.f);            // U * 2^17
    q = q > 32639 ? 32639 : (q < -32639 ? -32639 : q);
    int a = (q + 128) >> 8;
    int d = q - (a << 8);
    lc[(k << 4) + cc]  = (signed char)a;
    ldq[(k << 4) + cc] = (signed char)d;
  }
  __syncthreads();
#pragma unroll
  for (int rep = 0; rep < 4; rep++){
    int idx = rep * 256 + tid;                   // 0..1023
    int kt = idx >> 6, lane = idx & 63;
    int n = lane & 15, quad = lane >> 4;
    union { signed char b[16]; i32x4 v; } cb_, db_;
#pragma unroll
    for (int j = 0; j < 16; j++){
      int k = (kt << 6) + (quad << 4) + j;
      cb_.b[j] = lc[(k << 4) + n];
      db_.b[j] = ldq[(k << 4) + n];
    }
    size_t base = (size_t)((((nb << 2) + nt4) * 16 + kt) * 2) * 1024;
    *(i32x4*)(img + base + (size_t)lane * 16)        = cb_.v;
    *(i32x4*)(img + base + 1024 + (size_t)lane * 16) = db_.v;
  }
}

// ---------------------------------------------------------------------------
// gates GEMM: xg[256*tc][4096] = token-gathered ebimg x Wimg + bias (3-product).
// R10: BOTH operands staged via global_load_lds width=16 (Common-mistake #1):
// linear LDS dest + inverse-XOR-swizzled per-lane global source (rule #21);
// read side keeps the same XOR -> layout identical to the reg-staged version.
// A = ebimg (u16 image, gather by token: global source is per-lane -> legal).
// ---------------------------------------------------------------------------
__global__ void __launch_bounds__(256) gemm_gates(
    const unsigned short* __restrict__ Aimg, const unsigned short* __restrict__ Bimg,
    const float* __restrict__ bias, float* __restrict__ D,
    const int* __restrict__ seq, int c0, int tcsh, int* __restrict__ prog)
{
  __shared__ __align__(16) char lds[16384];   // A 8KB | B 8KB
  __shared__ int stok[128];
  const int tid = threadIdx.x, lane = tid & 63, wv = tid >> 6;
  const int quad = lane >> 4, nlo = lane & 15;
  const int wm = wv & 1, wn = wv >> 1;
  const int rowbase = (blockIdx.x >> 5) << 7;   // 32 col-tiles
  const int colbase = (blockIdx.x & 31) << 7;
  const int tcm1 = (1 << tcsh) - 1;
  if (blockIdx.x == 0 && tid == 0) prog[5] = 1;
  if (tid < 128){
    int r = rowbase + tid;
    stok[tid] = seq[((r >> tcsh) << 7) + c0 + (r & tcm1)];
  }
  __syncthreads();

  f32x4 acc[4][4];
#pragma unroll
  for (int i = 0; i < 4; i++)
#pragma unroll
    for (int j = 0; j < 4; j++) acc[i][j] = (f32x4){0.f, 0.f, 0.f, 0.f};

  // fixed per-lane staging geometry: row=gidx>>2, sg=gidx&3, src chunk XOR'd
  const unsigned short* asrc[2]; const unsigned short* bsrc[2];
  char* adst[2]; char* bdst[2];
#pragma unroll
  for (int p = 0; p < 2; p++){
    int gidx = p * 256 + tid;
    int row = gidx >> 2, sg = gidx & 3;
    int sgs = sg ^ ((row >> 1) & 3);
    asrc[p] = Aimg + (size_t)stok[row] * 512 + sgs * 8;
    bsrc[p] = Bimg + (size_t)(colbase + row) * 512 + sgs * 8;
    adst[p] = &lds[p * 4096 + wv * 1024];
    bdst[p] = &lds[8192 + p * 4096 + wv * 1024];
  }

#pragma unroll 2
  for (int c = 0; c < 24; c++){
    int k0 = c * 32;
    int seg = (k0 >= 512) ? 2 : (k0 >= 256 ? 1 : 0);
    int acol = k0 - seg * 256;
    int aoff = (seg == 1 ? 256 : 0) + acol;
    int boff = (seg == 2 ? 256 : 0) + acol;
    __syncthreads();                       // prior tile fully consumed
#pragma unroll
    for (int p = 0; p < 2; p++){
      gl_lds16(asrc[p] + aoff, adst[p]);
      gl_lds16(bsrc[p] + boff, bdst[p]);
    }
    __syncthreads();                       // vmcnt(0) drained before barrier
    bf16x8 af[4], bfr[4];
#pragma unroll
    for (int mt = 0; mt < 4; mt++){
      int r = wm * 64 + mt * 16 + nlo;
      af[mt] = *(const bf16x8*)(&lds[r * 64 + ((quad ^ ((r >> 1) & 3)) << 4)]);
    }
#pragma unroll
    for (int nt = 0; nt < 4; nt++){
      int r = wn * 64 + nt * 16 + nlo;
      bfr[nt] = *(const bf16x8*)(&lds[8192 + r * 64 + ((quad ^ ((r >> 1) & 3)) << 4)]);
    }
#pragma unroll
    for (int mt = 0; mt < 4; mt++)
#pragma unroll
      for (int nt = 0; nt < 4; nt++)
        acc[mt][nt] = __builtin_amdgcn_mfma_f32_16x16x32_bf16(af[mt], bfr[nt], acc[mt][nt], 0, 0, 0);
  }

  float bs[4];
#pragma unroll
  for (int nt = 0; nt < 4; nt++) bs[nt] = bias[colbase + wn * 64 + nt * 16 + nlo];
#pragma unroll
  for (int mt = 0; mt < 4; mt++)
#pragma unroll
    for (int nt = 0; nt < 4; nt++){
      int col = colbase + wn * 64 + nt * 16 + nlo;
#pragma unroll
      for (int r = 0; r < 4; r++){
        int row = rowbase + wm * 64 + mt * 16 + quad * 4 + r;
        D[(size_t)row * 4096 + col] = acc[mt][nt][r] + bs[nt];
      }
    }
}

// ---------------------------------------------------------------------------
// output GEMM: out[b*128+c0+s][1024] = ohol x fcw + fcb (3-product, K'=3072)
// R10: both operands (preformatted u16 images) staged via global_load_lds.
// ---------------------------------------------------------------------------
__global__ void __launch_bounds__(256) gemm_out(
    const unsigned short* __restrict__ ohol, const unsigned short* __restrict__ Bimg,
    const float* __restrict__ bias, float* __restrict__ D,
    int c0, int tcsh, int* __restrict__ prog)
{
  __shared__ __align__(16) char lds[16384];
  const int tid = threadIdx.x, lane = tid & 63, wv = tid >> 6;
  const int quad = lane >> 4, nlo = lane & 15;
  const int wm = wv & 1, wn = wv >> 1;
  const int rowbase = (blockIdx.x >> 3) << 7;   // 8 col-tiles
  const int colbase = (blockIdx.x & 7) << 7;
  const int tcm1 = (1 << tcsh) - 1;
  if (blockIdx.x == 0 && tid == 0) prog[7] = 1;

  f32x4 acc[4][4];
#pragma unroll
  for (int i = 0; i < 4; i++)
#pragma unroll
    for (int j = 0; j < 4; j++) acc[i][j] = (f32x4){0.f, 0.f, 0.f, 0.f};

  const unsigned short* asrc[2]; const unsigned short* bsrc[2];
  char* adst[2]; char* bdst[2];
#pragma unroll
  for (int p = 0; p < 2; p++){
    int gidx = p * 256 + tid;
    int row = gidx >> 2, sg = gidx & 3;
    int sgs = sg ^ ((row >> 1) & 3);
    asrc[p] = ohol + (size_t)(rowbase + row) * 2048 + sgs * 8;
    bsrc[p] = Bimg + (size_t)(colbase + row) * 2048 + sgs * 8;
    adst[p] = &lds[p * 4096 + wv * 1024];
    bdst[p] = &lds[8192 + p * 4096 + wv * 1024];
  }

#pragma unroll 2
  for (int c = 0; c < 96; c++){
    int k0 = c * 32;
    int seg = (k0 >= 2048) ? 2 : (k0 >= 1024 ? 1 : 0);
    int acol = k0 - seg * 1024;
    int aoff = (seg == 1 ? 1024 : 0) + acol;
    int boff = (seg == 2 ? 1024 : 0) + acol;
    __syncthreads();
#pragma unroll
    for (int p = 0; p < 2; p++){
      gl_lds16(asrc[p] + aoff, adst[p]);
      gl_lds16(bsrc[p] + boff, bdst[p]);
    }
    __syncthreads();
    bf16x8 af[4], bfr[4];
#pragma unroll
    for (int mt = 0; mt < 4; mt++){
      int r = wm * 64 + mt * 16 + nlo;
      af[mt] = *(const bf16x8*)(&lds[r * 64 + ((quad ^ ((r >> 1) & 3)) << 4)]);
    }
#pragma unroll
    for (int nt = 0; nt < 4; nt++){
      int r = wn * 64 + nt * 16 + nlo;
      bfr[nt] = *(const bf16x8*)(&lds[8192 + r * 64 + ((quad ^ ((r >> 1) & 3)) << 4)]);
    }
#pragma unroll
    for (int mt = 0; mt < 4; mt++)
#pragma unroll
      for (int nt = 0; nt < 4; nt++)
        acc[mt][nt] = __builtin_amdgcn_mfma_f32_16x16x32_bf16(af[mt], bfr[nt], acc[mt][nt], 0, 0, 0);
  }

  float bs[4];
#pragma unroll
  for (int nt = 0; nt < 4; nt++) bs[nt] = bias[colbase + wn * 64 + nt * 16 + nlo];
#pragma unroll
  for (int mt = 0; mt < 4; mt++)
#pragma unroll
    for (int nt = 0; nt < 4; nt++){
      int col = colbase + wn * 64 + nt * 16 + nlo;
#pragma unroll
      for (int r = 0; r < 4; r++){
        int row = rowbase + wm * 64 + mt * 16 + quad * 4 + r;
        int drow = ((row >> tcsh) << 7) + c0 + (row & tcm1);
        D[(size_t)drow * 1024 + col] = acc[mt][nt][r] + bs[nt];
      }
    }
}

// ---------------------------------------------------------------------------
// per-mb-group FLAG-ARRAY barrier (64 WGs), ZERO cache maintenance (R9-proven):
//   Writer: h(t+1) via RETURNING agent-scope 32-bit atomic_exchange (result
//   consumed) -> executes at the MALL; vmcnt retires on response -> after
//   __syncthreads() all h-words are AT the coherence point.
//   Reader: h addresses are LAUNCH-FRESH (hh slot history, 33 distinct slots
//   per launch) -> no stale copies possible -> plain cached loads, NO fence.
//   - wait: wave 0 polls all 64 flags IN PARALLEL (lane i -> flag[i]).
//   - workgroup acquire fence = compiler-only ordering (no cache ops).
// ---------------------------------------------------------------------------
DEVINL void mbbar(int* flags, int nb, int t, int wv, int lane){
  __syncthreads();   // vmcnt(0) per wave: all h-exchanges RESPONDED (at MALL)
  if (wv == 0){
    if (lane == 0)
      __hip_atomic_store(&flags[nb], t + 1, __ATOMIC_RELAXED, __HIP_MEMORY_SCOPE_AGENT);
    const int tgt = t + 1;
    for (;;){
      int v = __hip_atomic_load(&flags[lane], __ATOMIC_RELAXED, __HIP_MEMORY_SCOPE_AGENT);
      if (__ballot(v >= tgt) == ~0ull) break;
      __builtin_amdgcn_s_sleep(1);
    }
    __builtin_amdgcn_fence(__ATOMIC_ACQUIRE, "workgroup");  // compiler ordering only
  }
  __syncthreads();
}

// ---------------------------------------------------------------------------
// persistent LSTM recurrence, tc steps/launch.  256 WGs x 512 thr = 4 mb x 64 nb.
// Identical to R9 except HH uses 33 rotating slots (t % 33): all slot indices
// within one launch are distinct -> freshness argument unchanged; cross-launch
// reuse covered by dispatch-boundary cache invalidation (relied on since R1).
// ---------------------------------------------------------------------------
__global__ void __launch_bounds__(512, 2) lstm_rec(
    const float* __restrict__ xg,        // [256*tc][4096] f32, row = b*tc+s
    const signed char* __restrict__ uimg,
    const int* __restrict__ len,
    signed char* __restrict__ hh,        // [33 slot][256][1024] u16 packed history
    float* __restrict__ cbuf,            // [256][1024] f32
    unsigned short* __restrict__ ohol,   // [256*tc][hi1024|lo1024]
    int* __restrict__ barbase,           // flags[mb] at barbase + mb*64 ints
    int* __restrict__ prog,
    int c0, int tcsh)
{
  // LDS: [0,16384) h tile (2 pl x 64 r x 128B, 16B-granule XOR swizzle);
  //      [16384,32768) xg f32 [64][64]; [32768,50176) z f32 [64][68]
  __shared__ __align__(16) char lds[50176];
  const int tc = 1 << tcsh;
  const int wg = blockIdx.x, mb = wg >> 6, nb = wg & 63;
  const int tid = threadIdx.x, lane = tid & 63, wv = tid >> 6;  // wv 0..7
  const int quad = lane >> 4, nlo = lane & 15;
  const int mh = wv & 1, g = wv >> 1;                           // gate 0..3
  int* flags = barbase + (mb << 6);
  if (wg == 0 && tid == 0) prog[6] = 1;

  const unsigned short* hh2 = (const unsigned short*)hh;

  // ---- U fragments -> registers: gate g, u-block nb, 16 kt x 2 planes ----
  i32x4 Bf[16][2];
#pragma unroll
  for (int kt = 0; kt < 16; kt++)
#pragma unroll
    for (int pl = 0; pl < 2; pl++){
      size_t off = (size_t)((((nb << 2) + g) * 16 + kt) * 2 + pl);
      off = (off * 64 + lane) << 4;
      Bf[kt][pl] = *(const i32x4*)(uimg + off);
    }

  // ---- elementwise mapping: thread = (1 row x 2 adjacent cols) ----
  const int erow = tid >> 3;            // 0..63 local row
  const int ecp  = tid & 7;             // col-pair index
  const int ecol0 = ecp << 1;           // local col (even)
  const int ucol0 = (nb << 4) + ecol0;  // global u col (even)
  const int bglob = (mb << 6) + erow;
  const int lenr = len[bglob];
  float cst[2], hst[2];
#pragma unroll
  for (int r = 0; r < 2; r++){
    cst[r] = cbuf[(size_t)bglob * 1024 + ucol0 + r];
    unsigned short e = hh2[(size_t)hslot(c0) * 262144 + (size_t)bglob * 1024 + ucol0 + r];
    int a = (signed char)(e >> 8), b_ = (signed char)(e & 255);
    hst[r] = (float)(a * 256 + b_) * (1.0f / 32512.0f);
  }

  // xg prefetch: issued before mbbar so HBM latency hides under the spin.
  float4 xreg[2];
  auto load_x = [&](int s){
#pragma unroll
    for (int it = 0; it < 2; it++){
      int idx = it * 512 + tid;
      int row = idx >> 4, c4 = idx & 15;
      xreg[it] = *(const float4*)(xg + (size_t)((((mb << 6) + row) << tcsh) + s) * 4096
                                  + (c4 >> 2) * 1024 + (nb << 4) + ((c4 & 3) << 2));
    }
  };
  load_x(0);

  // h staging mapping: thread = (1 row x one 32B packed block of 8)
  const int hrw = tid >> 3, hsub = tid & 7;

#pragma unroll 1
  for (int s = 0; s < tc; s++){
    const int t = c0 + s;
    // input h of step t lives at slot hslot(t) (launch-fresh -> plain loads)
    const signed char* hsrc = hh + (size_t)hslot(t) * 524288 + (size_t)(mb << 6) * 2048;

    i32x4 accH[2], accM[2], accL[2];
#pragma unroll
    for (int m = 0; m < 2; m++){
      accH[m] = (i32x4){0,0,0,0};
      accM[m] = (i32x4){0,0,0,0};
      accL[m] = (i32x4){0,0,0,0};
    }

    int4 hregA[2], hregB[2];
    auto load_hto = [&](int c, int4* dst){
      const signed char* p = hsrc + (size_t)hrw * 2048 + c * 256 + hsub * 32;
      dst[0] = *(const int4*)p;
      dst[1] = *(const int4*)(p + 16);
    };
    // split packed u16 block (16 cols) -> hi plane 16B + lo plane 16B, write
    // with the R5 16B-granule swizzle (low bank-conflict layout).
    auto write_hf = [&](const int4* src){
      unsigned r0 = (unsigned)src[0].x, r1 = (unsigned)src[0].y;
      unsigned r2 = (unsigned)src[0].z, r3 = (unsigned)src[0].w;
      unsigned r4 = (unsigned)src[1].x, r5 = (unsigned)src[1].y;
      unsigned r6 = (unsigned)src[1].z, r7 = (unsigned)src[1].w;
      i32x4 lo, hi;
      lo[0] = __builtin_amdgcn_perm(r1, r0, 0x06040200u);
      lo[1] = __builtin_amdgcn_perm(r3, r2, 0x06040200u);
      lo[2] = __builtin_amdgcn_perm(r5, r4, 0x06040200u);
      lo[3] = __builtin_amdgcn_perm(r7, r6, 0x06040200u);
      hi[0] = __builtin_amdgcn_perm(r1, r0, 0x07050301u);
      hi[1] = __builtin_amdgcn_perm(r3, r2, 0x07050301u);
      hi[2] = __builtin_amdgcn_perm(r5, r4, 0x07050301u);
      hi[3] = __builtin_amdgcn_perm(r7, r6, 0x07050301u);
      int sw = (hsub ^ (hrw & 7)) << 4;
      *(i32x4*)(&lds[hrw * 128 + sw])        = hi;   // plane 0 = hi bytes (a)
      *(i32x4*)(&lds[8192 + hrw * 128 + sw]) = lo;   // plane 1 = lo bytes (b)
    };

    load_hto(0, hregA);
    load_hto(1, hregB);

#pragma unroll                         // FULL unroll: Bf[kt] compile-time
    for (int c = 0; c < 8; c++){
      __syncthreads();
      if ((c & 1) == 0) write_hf(hregA); else write_hf(hregB);
      if (c == 0){
#pragma unroll
        for (int it = 0; it < 2; it++){
          int idx = it * 512 + tid;
          int row = idx >> 4, c4 = idx & 15;
          *(float4*)(&lds[16384 + row * 256 + c4 * 16]) = xreg[it];
        }
      }
      __syncthreads();
      if (c + 2 < 8){
        if ((c & 1) == 0) load_hto(c + 2, hregA); else load_hto(c + 2, hregB);
      }
#pragma unroll
      for (int kt2 = 0; kt2 < 2; kt2++){
        const int kt = c * 2 + kt2;
        i32x4 Af[2][2];
#pragma unroll
        for (int m = 0; m < 2; m++){
          int hrow = (mh << 5) + (m << 4) + nlo;
          int sgl = ((kt2 << 2) + quad) ^ (hrow & 7);
          Af[m][0] = *(const i32x4*)(&lds[hrow * 128 + (sgl << 4)]);
          Af[m][1] = *(const i32x4*)(&lds[8192 + hrow * 128 + (sgl << 4)]);
        }
#pragma unroll
        for (int m = 0; m < 2; m++){
          accH[m] = __builtin_amdgcn_mfma_i32_16x16x64_i8(Af[m][0], Bf[kt][0], accH[m], 0, 0, 0);
          accM[m] = __builtin_amdgcn_mfma_i32_16x16x64_i8(Af[m][0], Bf[kt][1], accM[m], 0, 0, 0);
          accM[m] = __builtin_amdgcn_mfma_i32_16x16x64_i8(Af[m][1], Bf[kt][0], accM[m], 0, 0, 0);
          accL[m] = __builtin_amdgcn_mfma_i32_16x16x64_i8(Af[m][1], Bf[kt][1], accL[m], 0, 0, 0);
        }
      }
    }
    __syncthreads();

    // prefetch next step's xg under the z/elementwise/barrier phases
    if (s + 1 < tc) load_x(s + 1);

    // ---- z = (65536*accH + 256*accM + accL)/(32512*2^17) -> LDS ----
    const float cH = 1.0f / 65024.0f;
    const float cM = 1.0f / 16646144.0f;
    const float cL = 1.0f / 4261412864.0f;
#pragma unroll
    for (int m = 0; m < 2; m++){
#pragma unroll
      for (int r = 0; r < 4; r++){
        float z = (float)accH[m][r] * cH
                + (float)accM[m][r] * cM
                + (float)accL[m][r] * cL;
        int zrow = (mh << 5) + (m << 4) + (quad << 2) + r;
        *(float*)(&lds[32768 + (((zrow * 68) + g * 16 + nlo) << 2)]) = z;
      }
    }
    __syncthreads();

    {
      float ho16[2];
      unsigned enc2 = 0;
#pragma unroll
      for (int r = 0; r < 2; r++){
        int col = ecol0 + r;
        float zi = *(const float*)(&lds[32768 + (((erow * 68) + 0  + col) << 2)])
                 + *(const float*)(&lds[16384 + (((erow << 6) + 0  + col) << 2)]);
        float zf = *(const float*)(&lds[32768 + (((erow * 68) + 16 + col) << 2)])
                 + *(const float*)(&lds[16384 + (((erow << 6) + 16 + col) << 2)]);
        float zg = *(const float*)(&lds[32768 + (((erow * 68) + 32 + col) << 2)])
                 + *(const float*)(&lds[16384 + (((erow << 6) + 32 + col) << 2)]);
        float zo = *(const float*)(&lds[32768 + (((erow * 68) + 48 + col) << 2)])
                 + *(const float*)(&lds[16384 + (((erow << 6) + 48 + col) << 2)]);
        float iv = sigm(zi), fv = sigm(zf), ov = sigm(zo), gv = tanhfast(zg);
        float cn = fv * cst[r] + iv * gv;
        float hn = ov * tanhfast(cn);
        bool vld = (t < lenr);
        cst[r] = vld ? cn : cst[r];
        hst[r] = vld ? hn : hst[r];
        ho16[r] = vld ? hn : 0.f;
        int H = (int)rintf(hst[r] * 32512.f);
        H = H > 32512 ? 32512 : (H < -32512 ? -32512 : H);
        int a = (H + 128) >> 8;
        int b_ = H - (a << 8);
        unsigned e = (((unsigned)a & 255u) << 8) | ((unsigned)b_ & 255u);
        enc2 |= e << (r * 16);
      }
      // ohol: 2 adjacent cols -> u32 stores (hi plane, lo plane)
      size_t orow = ((size_t)bglob << tcsh) + s;
      unsigned hi2 = (unsigned)(__float_as_uint(ho16[0]) >> 16)
                   | ((unsigned)(__float_as_uint(ho16[1]) >> 16) << 16);
      unsigned lo2 = (unsigned)bf16lo(ho16[0]) | ((unsigned)bf16lo(ho16[1]) << 16);
      *(unsigned*)(ohol + orow * 2048 + ucol0)        = hi2;
      *(unsigned*)(ohol + orow * 2048 + 1024 + ucol0) = lo2;
      // h(t+1) -> FRESH slot: ONE returning 32-bit atomic exchange (provable
      // release — vmcnt retires only on MALL response; see mbbar).
      unsigned* hp = (unsigned*)(hh + (size_t)hslot(t + 1) * 524288
                                 + ((size_t)bglob * 1024 + ucol0) * 2);
      unsigned old = __hip_atomic_exchange(hp, enc2, __ATOMIC_RELAXED,
                                           __HIP_MEMORY_SCOPE_AGENT);
      asm volatile("" :: "v"(old));   // consume result -> returning form
    }
    mbbar(flags, nb, t, wv, lane);
  }

#pragma unroll
  for (int r = 0; r < 2; r++)
    cbuf[(size_t)bglob * 1024 + ucol0 + r] = cst[r];
}

// ---------------------------------------------------------------------------
extern "C" void kernel_launch(void* const* d_in, const int* in_sizes, int n_in,
                              void* d_out, int out_size, void* d_ws, size_t ws_size,
                              hipStream_t stream)
{
  const int*   seq = (const int*)  d_in[0];
  const float* emb = (const float*)d_in[1];
  const float* Wm  = (const float*)d_in[2];
  const float* Um  = (const float*)d_in[3];
  const float* bv  = (const float*)d_in[4];
  const float* fcW = (const float*)d_in[5];
  const float* fcb = (const float*)d_in[6];
  float* out = (float*)d_out;
  char* ws = (char*)d_ws;

  // marker: survives iff no kernel/memset below ever touches d_out
  hipMemsetAsync(d_out, 0x42, 256, stream);   // 64 floats = 48.566

  size_t off = 0;
  unsigned short* wim = (unsigned short*)(ws + off); off += SZ_WIM;
  unsigned short* fcw = (unsigned short*)(ws + off); off += SZ_FCW;
  signed char*    uim = (signed char*)(ws + off);    off += SZ_UIM;
  unsigned short* ebi = (unsigned short*)(ws + off); off += SZ_EBI;
  signed char*    hh  = (signed char*)(ws + off);    off += SZ_HH;
  float*          cb  = (float*)(ws + off);          off += SZ_CB;
  int*            len = (int*)(ws + off);            off += SZ_LEN;
  int*            diag= (int*)(ws + off);            off += SZ_DIAG;
  const size_t fixed = off;

  int tcsh = -1;
  for (int s = 5; s >= 0; s--)
    if (ws && fixed + (5242880ull << s) <= ws_size){ tcsh = s; break; }

  if (tcsh < 0){
    probe_fill<<<(out_size + 255) / 256, 256, 0, stream>>>(
        out, out_size, 1000.0f + (float)(ws_size >> 20));
    return;
  }
  const int tc = 1 << tcsh;

  float*          xgc  = (float*)(ws + fixed);
  unsigned short* ohol = (unsigned short*)(ws + fixed + (size_t)tc * 4194304);

  hipMemsetAsync(diag, 0, SZ_DIAG, stream);   // prog + per-mb barrier flags
  hipMemsetAsync(hh, 0, 524288, stream);      // h history slot 0 = 0 (enc(0)=0)
  hipMemsetAsync(cb, 0, SZ_CB, stream);       // c state = 0

  int* prog = diag;
  int* barbase = diag + 64;                   // flags: 4 mb x 64 ints, 256B apart

  len_kernel<<<256, 128, 0, stream>>>(seq, len, prog);
  prep_split_img<<<256, 256, 0, stream>>>(Wm, wim, 4096, 256, prog, 2);
  prep_split_img<<<256, 256, 0, stream>>>(fcW, fcw, 1024, 1024, prog, 3);
  prep_emb_img<<<10000, 256, 0, stream>>>(emb, ebi);
  prep_uimg<<<256, 256, 0, stream>>>(Um, uim, prog);

  for (int c0 = 0; c0 < 128; c0 += tc){
    gemm_gates<<<dim3((2 * tc) * 32), 256, 0, stream>>>(ebi, wim, bv, xgc, seq, c0, tcsh, prog);
    lstm_rec<<<dim3(256), 512, 0, stream>>>(xgc, uim, len, hh, cb, ohol, barbase, prog, c0, tcsh);
    gemm_out<<<dim3((2 * tc) * 8), 256, 0, stream>>>(ohol, fcw, fcb, out, c0, tcsh, prog);
  }

  diag_check<<<1, 64, 0, stream>>>(prog, out);
}